// Round 1
// baseline (186.620 us; speedup 1.0000x reference)
//
#include <hip/hip_runtime.h>
#include <hip/hip_bf16.h>

typedef __bf16 bf16;
typedef __bf16 bf16x4 __attribute__((ext_vector_type(4)));
typedef __bf16 bf16x8 __attribute__((ext_vector_type(8)));
typedef float  f32x4 __attribute__((ext_vector_type(4)));

#define MFMA16(a, b, c) __builtin_amdgcn_mfma_f32_16x16x32_bf16((a), (b), (c), 0, 0, 0)

// async 16B/lane global->LDS (m97). LDS dst = uniform base + lane*16.
#define GLOBAL_LOAD_LDS16(gp, lp)                                                     \
    __builtin_amdgcn_global_load_lds(                                                 \
        (const __attribute__((address_space(1))) void*)(gp),                          \
        (__attribute__((address_space(3))) void*)(lp), 16, 0, 0)

// ---------------------------------------------------------------------------
// fp32 -> bf16, two sources into one contiguous dst (8 elems/thread)
__global__ __launch_bounds__(256)
void cvt2(const float* __restrict__ s1, const float* __restrict__ s2,
          bf16* __restrict__ dst, int n1, int ntot)
{
    int i = blockIdx.x * 256 + threadIdx.x;
    if (i >= ntot) return;
    const float* s = (i < n1) ? s1 + (size_t)i * 8 : s2 + (size_t)(i - n1) * 8;
    f32x4 a = *reinterpret_cast<const f32x4*>(s);
    f32x4 b = *reinterpret_cast<const f32x4*>(s + 4);
    bf16x8 r;
#pragma unroll
    for (int u = 0; u < 4; u++) { r[u] = (bf16)a[u]; r[u + 4] = (bf16)b[u]; }
    *reinterpret_cast<bf16x8*>(dst + (size_t)i * 8) = r;
}

// ---------------------------------------------------------------------------
// QKV projection, ping-pong prefetch 2-phase (T3-minimum recipe):
// BK=32 slices ping-pong between the two LDS halves; slice s+1's
// global_load_lds is issued BEFORE slice s's ds_read+MFMA so the DMA latency
// hides under compute; one barrier per slice. 128x128 tiles, 768 blocks.
//  QKPATH=true  (n0<2048):  swapped MFMA -> qk[m][n] packed 8B along n.
//  QKPATH=false (V blocks): normal MFMA  -> vt[e][m] packed 8B along m.
template<bool QKPATH>
__device__ __forceinline__
void qkv_body(const bf16* __restrict__ A, const bf16* __restrict__ B,
              bf16* __restrict__ qk, bf16* __restrict__ vt,
              bf16* As, bf16* Bs, int m0, int n0)
{
    constexpr int M = 4096;
    const int t = threadIdx.x;
    const int w = t >> 6, lane = t & 63, quad = lane >> 4, ln16 = lane & 15;
    const int wr = (w >> 1) * 64, wc = (w & 1) * 64;
    const int srow = lane >> 2;        // 0..15 within 16-row group
    const int scol = (lane & 3) * 8;   // 0..24 within 32-col slice

    f32x4 acc[4][4] = {};

    // stage one BK=32 slice (A: 128x32 = 8KB = 8 wave-ops, same for B;
    // 4 waves -> 2 A ops + 2 B ops per wave) into LDS half (s&1)
    auto stage = [&](int s) {
        const int kc = s * 32;
        bf16* Ad = As + (s & 1) * 4096;
        bf16* Bd = Bs + (s & 1) * 4096;
#pragma unroll
        for (int p = 0; p < 2; p++) {
            const int o = w * 2 + p;   // 16-row group 0..7
            GLOBAL_LOAD_LDS16(A + (size_t)(m0 + o * 16 + srow) * 1024 + kc + scol,
                              Ad + o * 512);
            GLOBAL_LOAD_LDS16(B + (size_t)(n0 + o * 16 + srow) * 1024 + kc + scol,
                              Bd + o * 512);
        }
    };

    stage(0);
    asm volatile("s_waitcnt vmcnt(0)" ::: "memory");
    __syncthreads();

    for (int s = 0; s < 32; s++) {
        if (s < 31) stage(s + 1);      // prefetch next slice into other half

        const bf16* Ab = As + (s & 1) * 4096;
        const bf16* Bb = Bs + (s & 1) * 4096;
        bf16x8 af[4];
#pragma unroll
        for (int mb = 0; mb < 4; mb++)
            af[mb] = *reinterpret_cast<const bf16x8*>(
                Ab + (wr + mb * 16 + ln16) * 32 + quad * 8);
#pragma unroll
        for (int nb = 0; nb < 4; nb++) {
            bf16x8 bv = *reinterpret_cast<const bf16x8*>(
                Bb + (wc + nb * 16 + ln16) * 32 + quad * 8);
#pragma unroll
            for (int mb = 0; mb < 4; mb++) {
                if constexpr (QKPATH) acc[mb][nb] = MFMA16(bv, af[mb], acc[mb][nb]);
                else                  acc[mb][nb] = MFMA16(af[mb], bv, acc[mb][nb]);
            }
        }

        // drain this step's prefetch (issued ~whole compute phase ago),
        // then barrier: next iteration may read (s+1)&1 and overwrite s&1.
        asm volatile("s_waitcnt vmcnt(0)" ::: "memory");
        __syncthreads();
    }

    if constexpr (QKPATH) {
#pragma unroll
        for (int mb = 0; mb < 4; mb++)
#pragma unroll
            for (int nb = 0; nb < 4; nb++) {
                size_t idx = (size_t)(m0 + wr + mb * 16 + ln16) * 2048
                           + (n0 + wc + nb * 16 + quad * 4);
                bf16x4 v;
#pragma unroll
                for (int r = 0; r < 4; r++) v[r] = (bf16)acc[mb][nb][r];
                *reinterpret_cast<bf16x4*>(&qk[idx]) = v;
            }
    } else {
#pragma unroll
        for (int mb = 0; mb < 4; mb++)
#pragma unroll
            for (int nb = 0; nb < 4; nb++) {
                const int e = n0 - 2048 + wc + nb * 16 + ln16;
                size_t idx = (size_t)e * M + (m0 + wr + mb * 16 + quad * 4);
                bf16x4 v;
#pragma unroll
                for (int r = 0; r < 4; r++) v[r] = (bf16)acc[mb][nb][r];
                *reinterpret_cast<bf16x4*>(&vt[idx]) = v;
            }
    }
}

__global__ __launch_bounds__(256)
void gemm_qkv(const bf16* __restrict__ A, const bf16* __restrict__ B,
              bf16* __restrict__ qk, bf16* __restrict__ vt)
{
    __shared__ __align__(16) bf16 As[8192];  // 2 ping-pong halves x [128][32]
    __shared__ __align__(16) bf16 Bs[8192];
    const int m0 = blockIdx.y * 128, n0 = blockIdx.x * 128;
    if (n0 < 2048) qkv_body<true >(A, B, qk, vt, As, Bs, m0, n0);
    else           qkv_body<false>(A, B, qk, vt, As, Bs, m0, n0);
}

// ---------------------------------------------------------------------------
// Out projection v4: same ping-pong prefetch restructure as gemm_qkv.
// 64x64 tiles -> 1024 blocks (4/CU). BK=32 slices between the two LDS halves.
// Swapped MFMA -> packed f32x4 C-stores.
__global__ __launch_bounds__(256)
void gemm_out(const bf16* __restrict__ A, const bf16* __restrict__ Bw,
              float* __restrict__ C)
{
    __shared__ __align__(16) bf16 As[4096];  // 2 ping-pong halves x [64][32]
    __shared__ __align__(16) bf16 Bs[4096];

    const int t = threadIdx.x;
    const int w = t >> 6, lane = t & 63, quad = lane >> 4, ln16 = lane & 15;
    const int m0 = blockIdx.y * 64, n0 = blockIdx.x * 64;
    const int wr = (w >> 1) * 32, wc = (w & 1) * 32;
    const int srow = lane >> 2;
    const int scol = (lane & 3) * 8;

    f32x4 acc[2][2] = {};

    // one BK=32 slice: A 64x32 = 4KB = 4 wave-ops -> 1 A op + 1 B op per wave
    auto stage = [&](int s) {
        const int kc = s * 32;
        bf16* Ad = As + (s & 1) * 2048;
        bf16* Bd = Bs + (s & 1) * 2048;
        const int o = w;               // 16-row group 0..3
        GLOBAL_LOAD_LDS16(A  + (size_t)(m0 + o * 16 + srow) * 1024 + kc + scol,
                          Ad + o * 512);
        GLOBAL_LOAD_LDS16(Bw + (size_t)(n0 + o * 16 + srow) * 1024 + kc + scol,
                          Bd + o * 512);
    };

    stage(0);
    asm volatile("s_waitcnt vmcnt(0)" ::: "memory");
    __syncthreads();

    for (int s = 0; s < 32; s++) {
        if (s < 31) stage(s + 1);

        const bf16* Ab = As + (s & 1) * 2048;
        const bf16* Bb = Bs + (s & 1) * 2048;
        bf16x8 af[2];
#pragma unroll
        for (int mb = 0; mb < 2; mb++)
            af[mb] = *reinterpret_cast<const bf16x8*>(
                Ab + (wr + mb * 16 + ln16) * 32 + quad * 8);
#pragma unroll
        for (int nb = 0; nb < 2; nb++) {
            bf16x8 bv = *reinterpret_cast<const bf16x8*>(
                Bb + (wc + nb * 16 + ln16) * 32 + quad * 8);
#pragma unroll
            for (int mb = 0; mb < 2; mb++)
                acc[mb][nb] = MFMA16(bv, af[mb], acc[mb][nb]);  // swapped
        }

        asm volatile("s_waitcnt vmcnt(0)" ::: "memory");
        __syncthreads();
    }

    // lane: m = ...+ln16 fixed, n = ...+quad*4 + r -> packed f32x4 stores
#pragma unroll
    for (int mb = 0; mb < 2; mb++)
#pragma unroll
        for (int nb = 0; nb < 2; nb++) {
            size_t idx = (size_t)(m0 + wr + mb * 16 + ln16) * 1024
                       + (n0 + wc + nb * 16 + quad * 4);
            *reinterpret_cast<f32x4*>(&C[idx]) = acc[mb][nb];
        }
}

// ---------------------------------------------------------------------------
// Fused causal flash attention v6 (R7, proven 47.4 us) — unchanged.
__global__ __launch_bounds__(256)
void attn_flash6(const bf16* __restrict__ qk, const bf16* __restrict__ vt,
                 bf16* __restrict__ z)
{
    constexpr int Tn = 2048, Dm = 1024, QLD = 2048, VLD = 4096;
    constexpr int KP = 72;
    __shared__ __align__(16) bf16 Ks[64 * KP];
    __shared__ __align__(16) bf16 VTs[64 * KP];
    __shared__ __align__(16) bf16 Ps[64 * KP];

    const int t = threadIdx.x;
    const int w = t >> 6, lane = t & 63, quad = lane >> 4, ln16 = lane & 15;
    const int q = blockIdx.x >> 5, g = blockIdx.x & 31;
    const int s4 = q >> 3, q0i = q & 7;
    const int j = (s4 == 0) ? q0i : (s4 == 1) ? (15 - q0i)
                : (s4 == 2) ? (16 + q0i) : (31 - q0i);
    const int b = g >> 4, h = g & 15;
    const int q0 = j * 64;

    const bf16* Qb = qk + (size_t)b * Tn * QLD + h * 64;
    const bf16* Kb = Qb + 1024;
    const bf16* Vb = vt + (size_t)(h * 64) * VLD + b * Tn;

    constexpr float C2 = 0.125f * 1.44269504089f;
    bf16x8 qf[2];
#pragma unroll
    for (int kki = 0; kki < 2; kki++) {
        bf16x8 qv = *reinterpret_cast<const bf16x8*>(
            Qb + (size_t)(q0 + w * 16 + ln16) * QLD + kki * 32 + quad * 8);
#pragma unroll
        for (int u = 0; u < 8; u++) qf[kki][u] = (bf16)((float)qv[u] * C2);
    }

    bf16x8 vones;
#pragma unroll
    for (int u = 0; u < 8; u++) vones[u] = (bf16)1.0f;

    const int sr = t >> 3;
    const int sseg = (t & 7) * 8;

    bf16x8 kreg[2], vreg[2];
#pragma unroll
    for (int p = 0; p < 2; p++) {
        kreg[p] = *reinterpret_cast<const bf16x8*>(Kb + (size_t)(sr + p * 32) * QLD + sseg);
        vreg[p] = *reinterpret_cast<const bf16x8*>(Vb + (size_t)(sr + p * 32) * VLD + sseg);
    }

    f32x4 accO[5] = {};
    const int qloc = w * 16 + ln16;

    for (int kt = 0; kt <= j; kt++) {
        __syncthreads();
#pragma unroll
        for (int p = 0; p < 2; p++) {
            *reinterpret_cast<bf16x8*>(&Ks[(sr + p * 32) * KP + sseg]) = kreg[p];
            *reinterpret_cast<bf16x8*>(&VTs[(sr + p * 32) * KP + sseg]) = vreg[p];
        }
        __syncthreads();

        if (kt < j) {
            const int k1 = (kt + 1) * 64;
#pragma unroll
            for (int p = 0; p < 2; p++) {
                kreg[p] = *reinterpret_cast<const bf16x8*>(
                    Kb + (size_t)(k1 + sr + p * 32) * QLD + sseg);
                vreg[p] = *reinterpret_cast<const bf16x8*>(
                    Vb + (size_t)(sr + p * 32) * VLD + k1 + sseg);
            }
        }

        f32x4 aS[4] = {};
#pragma unroll
        for (int kki = 0; kki < 2; kki++)
#pragma unroll
            for (int nb = 0; nb < 4; nb++) {
                bf16x8 kb = *reinterpret_cast<const bf16x8*>(
                    &Ks[(nb * 16 + ln16) * KP + kki * 32 + quad * 8]);
                aS[nb] = MFMA16(kb, qf[kki], aS[nb]);
            }

        if (kt == j) {
#pragma unroll
            for (int nb = 0; nb < 4; nb++) {
                bf16x4 pv;
#pragma unroll
                for (int r = 0; r < 4; r++) {
                    float p = __builtin_amdgcn_exp2f(aS[nb][r]);
                    if ((nb * 16 + quad * 4 + r) > qloc) p = 0.f;
                    pv[r] = (bf16)p;
                }
                *reinterpret_cast<bf16x4*>(&Ps[qloc * KP + nb * 16 + quad * 4]) = pv;
            }
        } else {
#pragma unroll
            for (int nb = 0; nb < 4; nb++) {
                bf16x4 pv;
#pragma unroll
                for (int r = 0; r < 4; r++)
                    pv[r] = (bf16)__builtin_amdgcn_exp2f(aS[nb][r]);
                *reinterpret_cast<bf16x4*>(&Ps[qloc * KP + nb * 16 + quad * 4]) = pv;
            }
        }
        asm volatile("s_waitcnt lgkmcnt(0)" ::: "memory");

#pragma unroll
        for (int kki = 0; kki < 2; kki++) {
            bf16x8 pa = *reinterpret_cast<const bf16x8*>(
                &Ps[qloc * KP + kki * 32 + quad * 8]);
#pragma unroll
            for (int nb = 0; nb < 4; nb++) {
                bf16x8 vb = *reinterpret_cast<const bf16x8*>(
                    &VTs[(nb * 16 + ln16) * KP + kki * 32 + quad * 8]);
                accO[nb] = MFMA16(vb, pa, accO[nb]);
            }
            accO[4] = MFMA16(vones, pa, accO[4]);
        }
    }

    const float linv = 1.0f / accO[4][0];
    const size_t zr = ((size_t)b * Tn + q0 + qloc) * Dm + h * 64;
#pragma unroll
    for (int nb = 0; nb < 4; nb++) {
        bf16x4 v;
#pragma unroll
        for (int r = 0; r < 4; r++) v[r] = (bf16)(accO[nb][r] * linv);
        *reinterpret_cast<bf16x4*>(z + zr + nb * 16 + quad * 4) = v;
    }
}

// ---------------------------------------------------------------------------
extern "C" void kernel_launch(void* const* d_in, const int* in_sizes, int n_in,
                              void* d_out, int out_size, void* d_ws, size_t ws_size,
                              hipStream_t stream)
{
    constexpr int B = 2, T = 2048, D = 1024;
    constexpr int M = B * T;  // 4096

    const float* X    = (const float*)d_in[0];
    const float* Wqkv = (const float*)d_in[1];
    const float* Wout = (const float*)d_in[2];
    float* out = (float*)d_out;

    // ws: qk [M][2048] 16 MiB | vt [1024][M] 8 MiB | z [M][1024] 8 MiB
    bf16* qk  = (bf16*)d_ws;
    bf16* vt  = qk + (size_t)M * 2048;
    bf16* zbf = vt + (size_t)1024 * M;
    // d_out as scratch until gemm_out writes it (Xbf 8 MiB + Wqkvbf 6 MiB <= 16)
    bf16* Xbf    = (bf16*)d_out;
    bf16* Wqkvbf = Xbf + (size_t)M * D;
    // Woutbf reuses the vt region -- vt is dead after attn_flash6
    bf16* Woutbf = vt;

    dim3 blk(256);
    const int n1 = M * D / 8, n2 = 3 * D * D / 8;
    cvt2<<<(n1 + n2 + 255) / 256, blk, 0, stream>>>(X, Wqkv, Xbf, n1, n1 + n2);

    gemm_qkv<<<dim3(24, 32), blk, 0, stream>>>(Xbf, Wqkvbf, qk, vt);

    attn_flash6<<<dim3(1024), blk, 0, stream>>>(qk, vt, zbf);

    const int n3 = D * D / 8;
    cvt2<<<(n3 + 255) / 256, blk, 0, stream>>>(Wout, Wout, Woutbf, n3, n3);

    gemm_out<<<dim3(16, 64), blk, 0, stream>>>(zbf, Woutbf, out);
}

// Round 2
// 183.485 us; speedup vs baseline: 1.0171x; 1.0171x over previous
//
#include <hip/hip_runtime.h>
#include <hip/hip_bf16.h>

typedef __bf16 bf16;
typedef __bf16 bf16x4 __attribute__((ext_vector_type(4)));
typedef __bf16 bf16x8 __attribute__((ext_vector_type(8)));
typedef float  f32x4 __attribute__((ext_vector_type(4)));

#define MFMA16(a, b, c) __builtin_amdgcn_mfma_f32_16x16x32_bf16((a), (b), (c), 0, 0, 0)

// async 16B/lane global->LDS (m97). LDS dst = uniform base + lane*16.
#define GLOBAL_LOAD_LDS16(gp, lp)                                                     \
    __builtin_amdgcn_global_load_lds(                                                 \
        (const __attribute__((address_space(1))) void*)(gp),                          \
        (__attribute__((address_space(3))) void*)(lp), 16, 0, 0)

// ---------------------------------------------------------------------------
// fp32 -> bf16, two sources into one contiguous dst (8 elems/thread)
__global__ __launch_bounds__(256)
void cvt2(const float* __restrict__ s1, const float* __restrict__ s2,
          bf16* __restrict__ dst, int n1, int ntot)
{
    int i = blockIdx.x * 256 + threadIdx.x;
    if (i >= ntot) return;
    const float* s = (i < n1) ? s1 + (size_t)i * 8 : s2 + (size_t)(i - n1) * 8;
    f32x4 a = *reinterpret_cast<const f32x4*>(s);
    f32x4 b = *reinterpret_cast<const f32x4*>(s + 4);
    bf16x8 r;
#pragma unroll
    for (int u = 0; u < 4; u++) { r[u] = (bf16)a[u]; r[u + 4] = (bf16)b[u]; }
    *reinterpret_cast<bf16x8*>(dst + (size_t)i * 8) = r;
}

// ---------------------------------------------------------------------------
// QKV projection, T4 counted-vmcnt pipeline: BK=32 slices, 3-deep LDS buffer
// rotation, prefetch distance 2. Raw s_barriers (no compiler vmcnt(0) drain);
// the only waits are vmcnt(8) (newer prefetches stay in flight ACROSS the
// barrier) and compiler lgkmcnt for ds_read->MFMA. 128x128 tiles, 768 blocks,
// 48 KB LDS -> 3 blocks/CU (exactly the grid's demand).
//  QKPATH=true  (n0<2048):  swapped MFMA -> qk[m][n] packed 8B along n.
//  QKPATH=false (V blocks): normal MFMA  -> vt[e][m] packed 8B along m.
template<bool QKPATH>
__device__ __forceinline__
void qkv_body(const bf16* __restrict__ A, const bf16* __restrict__ B,
              bf16* __restrict__ qk, bf16* __restrict__ vt,
              bf16* As, bf16* Bs, int m0, int n0)
{
    constexpr int M = 4096;
    const int t = threadIdx.x;
    const int w = t >> 6, lane = t & 63, quad = lane >> 4, ln16 = lane & 15;
    const int wr = (w >> 1) * 64, wc = (w & 1) * 64;
    const int srow = lane >> 2;        // 0..15 within 16-row group
    const int scol = (lane & 3) * 8;   // 0..24 within 32-col slice

    f32x4 acc[4][4] = {};

    // stage slice s (128 rows x 32 cols = 8 KB each of A,B) into buffer s%3.
    // 4 waves x 2 row-groups x {A,B} = 4 VMEM instructions per wave.
    auto stage = [&](int s) {
        const int kc = s * 32;
        bf16* Ad = As + (s % 3) * 4096;
        bf16* Bd = Bs + (s % 3) * 4096;
#pragma unroll
        for (int p = 0; p < 2; p++) {
            const int o = w * 2 + p;   // 16-row group 0..7
            GLOBAL_LOAD_LDS16(A + (size_t)(m0 + o * 16 + srow) * 1024 + kc + scol,
                              Ad + o * 512);
            GLOBAL_LOAD_LDS16(B + (size_t)(n0 + o * 16 + srow) * 1024 + kc + scol,
                              Bd + o * 512);
        }
    };

    stage(0);   // 4 VMEM in flight
    stage(1);   // 8 VMEM in flight

    for (int s = 0; s < 32; s++) {
        // prefetch distance 2; counted wait retires exactly slice s's 4 ops.
        if (s < 30) {
            stage(s + 2);   // 12 in flight; writes buf[(s-1)%3], last read at
                            // compute(s-1) -- separated by iter s-1's barrier.
            asm volatile("s_waitcnt vmcnt(8)" ::: "memory");
        } else if (s == 30) {
            asm volatile("s_waitcnt vmcnt(4)" ::: "memory");
        } else {
            asm volatile("s_waitcnt vmcnt(0)" ::: "memory");
        }
        __builtin_amdgcn_s_barrier();          // all waves' slice-s data in LDS
        __builtin_amdgcn_sched_barrier(0);

        const bf16* Ab = As + (s % 3) * 4096;
        const bf16* Bb = Bs + (s % 3) * 4096;
        bf16x8 af[4];
#pragma unroll
        for (int mb = 0; mb < 4; mb++)
            af[mb] = *reinterpret_cast<const bf16x8*>(
                Ab + (wr + mb * 16 + ln16) * 32 + quad * 8);
#pragma unroll
        for (int nb = 0; nb < 4; nb++) {
            bf16x8 bv = *reinterpret_cast<const bf16x8*>(
                Bb + (wc + nb * 16 + ln16) * 32 + quad * 8);
#pragma unroll
            for (int mb = 0; mb < 4; mb++) {
                if constexpr (QKPATH) acc[mb][nb] = MFMA16(bv, af[mb], acc[mb][nb]);
                else                  acc[mb][nb] = MFMA16(af[mb], bv, acc[mb][nb]);
            }
        }

        __builtin_amdgcn_sched_barrier(0);
        __builtin_amdgcn_s_barrier();          // all waves done reading buf[s%3]
    }

    if constexpr (QKPATH) {
#pragma unroll
        for (int mb = 0; mb < 4; mb++)
#pragma unroll
            for (int nb = 0; nb < 4; nb++) {
                size_t idx = (size_t)(m0 + wr + mb * 16 + ln16) * 2048
                           + (n0 + wc + nb * 16 + quad * 4);
                bf16x4 v;
#pragma unroll
                for (int r = 0; r < 4; r++) v[r] = (bf16)acc[mb][nb][r];
                *reinterpret_cast<bf16x4*>(&qk[idx]) = v;
            }
    } else {
#pragma unroll
        for (int mb = 0; mb < 4; mb++)
#pragma unroll
            for (int nb = 0; nb < 4; nb++) {
                const int e = n0 - 2048 + wc + nb * 16 + ln16;
                size_t idx = (size_t)e * M + (m0 + wr + mb * 16 + quad * 4);
                bf16x4 v;
#pragma unroll
                for (int r = 0; r < 4; r++) v[r] = (bf16)acc[mb][nb][r];
                *reinterpret_cast<bf16x4*>(&vt[idx]) = v;
            }
    }
}

__global__ __launch_bounds__(256)
void gemm_qkv(const bf16* __restrict__ A, const bf16* __restrict__ B,
              bf16* __restrict__ qk, bf16* __restrict__ vt)
{
    __shared__ __align__(16) bf16 As[12288];  // 3 rotating [128][32] buffers
    __shared__ __align__(16) bf16 Bs[12288];
    const int m0 = blockIdx.y * 128, n0 = blockIdx.x * 128;
    if (n0 < 2048) qkv_body<true >(A, B, qk, vt, As, Bs, m0, n0);
    else           qkv_body<false>(A, B, qk, vt, As, Bs, m0, n0);
}

// ---------------------------------------------------------------------------
// Out projection v5: identical T4 counted-vmcnt pipeline. 64x64 tiles,
// 1024 blocks (4/CU), BK=32 slices, 3-deep rotation, distance-2 prefetch.
// 24 KB LDS. stage = 2 VMEM instr/wave -> steady-state vmcnt(4).
__global__ __launch_bounds__(256)
void gemm_out(const bf16* __restrict__ A, const bf16* __restrict__ Bw,
              float* __restrict__ C)
{
    __shared__ __align__(16) bf16 As[6144];  // 3 rotating [64][32] buffers
    __shared__ __align__(16) bf16 Bs[6144];

    const int t = threadIdx.x;
    const int w = t >> 6, lane = t & 63, quad = lane >> 4, ln16 = lane & 15;
    const int m0 = blockIdx.y * 64, n0 = blockIdx.x * 64;
    const int wr = (w >> 1) * 32, wc = (w & 1) * 32;
    const int srow = lane >> 2;
    const int scol = (lane & 3) * 8;

    f32x4 acc[2][2] = {};

    // one slice: A 64x32 = 4 KB = 4 wave-ops across 4 waves -> 1 A + 1 B per wave
    auto stage = [&](int s) {
        const int kc = s * 32;
        bf16* Ad = As + (s % 3) * 2048;
        bf16* Bd = Bs + (s % 3) * 2048;
        GLOBAL_LOAD_LDS16(A  + (size_t)(m0 + w * 16 + srow) * 1024 + kc + scol,
                          Ad + w * 512);
        GLOBAL_LOAD_LDS16(Bw + (size_t)(n0 + w * 16 + srow) * 1024 + kc + scol,
                          Bd + w * 512);
    };

    stage(0);   // 2 in flight
    stage(1);   // 4 in flight

    for (int s = 0; s < 32; s++) {
        if (s < 30) {
            stage(s + 2);   // 6 in flight
            asm volatile("s_waitcnt vmcnt(4)" ::: "memory");
        } else if (s == 30) {
            asm volatile("s_waitcnt vmcnt(2)" ::: "memory");
        } else {
            asm volatile("s_waitcnt vmcnt(0)" ::: "memory");
        }
        __builtin_amdgcn_s_barrier();
        __builtin_amdgcn_sched_barrier(0);

        const bf16* Ab = As + (s % 3) * 2048;
        const bf16* Bb = Bs + (s % 3) * 2048;
        bf16x8 af[2];
#pragma unroll
        for (int mb = 0; mb < 2; mb++)
            af[mb] = *reinterpret_cast<const bf16x8*>(
                Ab + (wr + mb * 16 + ln16) * 32 + quad * 8);
#pragma unroll
        for (int nb = 0; nb < 2; nb++) {
            bf16x8 bv = *reinterpret_cast<const bf16x8*>(
                Bb + (wc + nb * 16 + ln16) * 32 + quad * 8);
#pragma unroll
            for (int mb = 0; mb < 2; mb++)
                acc[mb][nb] = MFMA16(bv, af[mb], acc[mb][nb]);  // swapped
        }

        __builtin_amdgcn_sched_barrier(0);
        __builtin_amdgcn_s_barrier();
    }

    // lane: m = ...+ln16 fixed, n = ...+quad*4 + r -> packed f32x4 stores
#pragma unroll
    for (int mb = 0; mb < 2; mb++)
#pragma unroll
        for (int nb = 0; nb < 2; nb++) {
            size_t idx = (size_t)(m0 + wr + mb * 16 + ln16) * 1024
                       + (n0 + wc + nb * 16 + quad * 4);
            *reinterpret_cast<f32x4*>(&C[idx]) = acc[mb][nb];
        }
}

// ---------------------------------------------------------------------------
// Fused causal flash attention v6 (R7, proven 47.4 us) — unchanged.
__global__ __launch_bounds__(256)
void attn_flash6(const bf16* __restrict__ qk, const bf16* __restrict__ vt,
                 bf16* __restrict__ z)
{
    constexpr int Tn = 2048, Dm = 1024, QLD = 2048, VLD = 4096;
    constexpr int KP = 72;
    __shared__ __align__(16) bf16 Ks[64 * KP];
    __shared__ __align__(16) bf16 VTs[64 * KP];
    __shared__ __align__(16) bf16 Ps[64 * KP];

    const int t = threadIdx.x;
    const int w = t >> 6, lane = t & 63, quad = lane >> 4, ln16 = lane & 15;
    const int q = blockIdx.x >> 5, g = blockIdx.x & 31;
    const int s4 = q >> 3, q0i = q & 7;
    const int j = (s4 == 0) ? q0i : (s4 == 1) ? (15 - q0i)
                : (s4 == 2) ? (16 + q0i) : (31 - q0i);
    const int b = g >> 4, h = g & 15;
    const int q0 = j * 64;

    const bf16* Qb = qk + (size_t)b * Tn * QLD + h * 64;
    const bf16* Kb = Qb + 1024;
    const bf16* Vb = vt + (size_t)(h * 64) * VLD + b * Tn;

    constexpr float C2 = 0.125f * 1.44269504089f;
    bf16x8 qf[2];
#pragma unroll
    for (int kki = 0; kki < 2; kki++) {
        bf16x8 qv = *reinterpret_cast<const bf16x8*>(
            Qb + (size_t)(q0 + w * 16 + ln16) * QLD + kki * 32 + quad * 8);
#pragma unroll
        for (int u = 0; u < 8; u++) qf[kki][u] = (bf16)((float)qv[u] * C2);
    }

    bf16x8 vones;
#pragma unroll
    for (int u = 0; u < 8; u++) vones[u] = (bf16)1.0f;

    const int sr = t >> 3;
    const int sseg = (t & 7) * 8;

    bf16x8 kreg[2], vreg[2];
#pragma unroll
    for (int p = 0; p < 2; p++) {
        kreg[p] = *reinterpret_cast<const bf16x8*>(Kb + (size_t)(sr + p * 32) * QLD + sseg);
        vreg[p] = *reinterpret_cast<const bf16x8*>(Vb + (size_t)(sr + p * 32) * VLD + sseg);
    }

    f32x4 accO[5] = {};
    const int qloc = w * 16 + ln16;

    for (int kt = 0; kt <= j; kt++) {
        __syncthreads();
#pragma unroll
        for (int p = 0; p < 2; p++) {
            *reinterpret_cast<bf16x8*>(&Ks[(sr + p * 32) * KP + sseg]) = kreg[p];
            *reinterpret_cast<bf16x8*>(&VTs[(sr + p * 32) * KP + sseg]) = vreg[p];
        }
        __syncthreads();

        if (kt < j) {
            const int k1 = (kt + 1) * 64;
#pragma unroll
            for (int p = 0; p < 2; p++) {
                kreg[p] = *reinterpret_cast<const bf16x8*>(
                    Kb + (size_t)(k1 + sr + p * 32) * QLD + sseg);
                vreg[p] = *reinterpret_cast<const bf16x8*>(
                    Vb + (size_t)(sr + p * 32) * VLD + k1 + sseg);
            }
        }

        f32x4 aS[4] = {};
#pragma unroll
        for (int kki = 0; kki < 2; kki++)
#pragma unroll
            for (int nb = 0; nb < 4; nb++) {
                bf16x8 kb = *reinterpret_cast<const bf16x8*>(
                    &Ks[(nb * 16 + ln16) * KP + kki * 32 + quad * 8]);
                aS[nb] = MFMA16(kb, qf[kki], aS[nb]);
            }

        if (kt == j) {
#pragma unroll
            for (int nb = 0; nb < 4; nb++) {
                bf16x4 pv;
#pragma unroll
                for (int r = 0; r < 4; r++) {
                    float p = __builtin_amdgcn_exp2f(aS[nb][r]);
                    if ((nb * 16 + quad * 4 + r) > qloc) p = 0.f;
                    pv[r] = (bf16)p;
                }
                *reinterpret_cast<bf16x4*>(&Ps[qloc * KP + nb * 16 + quad * 4]) = pv;
            }
        } else {
#pragma unroll
            for (int nb = 0; nb < 4; nb++) {
                bf16x4 pv;
#pragma unroll
                for (int r = 0; r < 4; r++)
                    pv[r] = (bf16)__builtin_amdgcn_exp2f(aS[nb][r]);
                *reinterpret_cast<bf16x4*>(&Ps[qloc * KP + nb * 16 + quad * 4]) = pv;
            }
        }
        asm volatile("s_waitcnt lgkmcnt(0)" ::: "memory");

#pragma unroll
        for (int kki = 0; kki < 2; kki++) {
            bf16x8 pa = *reinterpret_cast<const bf16x8*>(
                &Ps[qloc * KP + kki * 32 + quad * 8]);
#pragma unroll
            for (int nb = 0; nb < 4; nb++) {
                bf16x8 vb = *reinterpret_cast<const bf16x8*>(
                    &VTs[(nb * 16 + ln16) * KP + kki * 32 + quad * 8]);
                accO[nb] = MFMA16(vb, pa, accO[nb]);
            }
            accO[4] = MFMA16(vones, pa, accO[4]);
        }
    }

    const float linv = 1.0f / accO[4][0];
    const size_t zr = ((size_t)b * Tn + q0 + qloc) * Dm + h * 64;
#pragma unroll
    for (int nb = 0; nb < 4; nb++) {
        bf16x4 v;
#pragma unroll
        for (int r = 0; r < 4; r++) v[r] = (bf16)(accO[nb][r] * linv);
        *reinterpret_cast<bf16x4*>(z + zr + nb * 16 + quad * 4) = v;
    }
}

// ---------------------------------------------------------------------------
extern "C" void kernel_launch(void* const* d_in, const int* in_sizes, int n_in,
                              void* d_out, int out_size, void* d_ws, size_t ws_size,
                              hipStream_t stream)
{
    constexpr int B = 2, T = 2048, D = 1024;
    constexpr int M = B * T;  // 4096

    const float* X    = (const float*)d_in[0];
    const float* Wqkv = (const float*)d_in[1];
    const float* Wout = (const float*)d_in[2];
    float* out = (float*)d_out;

    // ws: qk [M][2048] 16 MiB | vt [1024][M] 8 MiB | z [M][1024] 8 MiB
    bf16* qk  = (bf16*)d_ws;
    bf16* vt  = qk + (size_t)M * 2048;
    bf16* zbf = vt + (size_t)1024 * M;
    // d_out as scratch until gemm_out writes it (Xbf 8 MiB + Wqkvbf 6 MiB <= 16)
    bf16* Xbf    = (bf16*)d_out;
    bf16* Wqkvbf = Xbf + (size_t)M * D;
    // Woutbf reuses the vt region -- vt is dead after attn_flash6
    bf16* Woutbf = vt;

    dim3 blk(256);
    const int n1 = M * D / 8, n2 = 3 * D * D / 8;
    cvt2<<<(n1 + n2 + 255) / 256, blk, 0, stream>>>(X, Wqkv, Xbf, n1, n1 + n2);

    gemm_qkv<<<dim3(24, 32), blk, 0, stream>>>(Xbf, Wqkvbf, qk, vt);

    attn_flash6<<<dim3(1024), blk, 0, stream>>>(qk, vt, zbf);

    const int n3 = D * D / 8;
    cvt2<<<(n3 + 255) / 256, blk, 0, stream>>>(Wout, Wout, Woutbf, n3, n3);

    gemm_out<<<dim3(16, 64), blk, 0, stream>>>(zbf, Woutbf, out);
}

// Round 4
// 175.511 us; speedup vs baseline: 1.0633x; 1.0454x over previous
//
#include <hip/hip_runtime.h>
#include <hip/hip_bf16.h>

typedef __bf16 bf16;
typedef __bf16 bf16x4 __attribute__((ext_vector_type(4)));
typedef __bf16 bf16x8 __attribute__((ext_vector_type(8)));
typedef float  f32x4 __attribute__((ext_vector_type(4)));

#define MFMA16(a, b, c) __builtin_amdgcn_mfma_f32_16x16x32_bf16((a), (b), (c), 0, 0, 0)

// async 16B/lane global->LDS (m97). LDS dst = uniform base + lane*16.
#define GLOBAL_LOAD_LDS16(gp, lp)                                                     \
    __builtin_amdgcn_global_load_lds(                                                 \
        (const __attribute__((address_space(1))) void*)(gp),                          \
        (__attribute__((address_space(3))) void*)(lp), 16, 0, 0)

// ---------------------------------------------------------------------------
// fp32 -> bf16, two sources into one contiguous dst (8 elems/thread)
__global__ __launch_bounds__(256)
void cvt2(const float* __restrict__ s1, const float* __restrict__ s2,
          bf16* __restrict__ dst, int n1, int ntot)
{
    int i = blockIdx.x * 256 + threadIdx.x;
    if (i >= ntot) return;
    const float* s = (i < n1) ? s1 + (size_t)i * 8 : s2 + (size_t)(i - n1) * 8;
    f32x4 a = *reinterpret_cast<const f32x4*>(s);
    f32x4 b = *reinterpret_cast<const f32x4*>(s + 4);
    bf16x8 r;
#pragma unroll
    for (int u = 0; u < 4; u++) { r[u] = (bf16)a[u]; r[u + 4] = (bf16)b[u]; }
    *reinterpret_cast<bf16x8*>(dst + (size_t)i * 8) = r;
}

// ---------------------------------------------------------------------------
// QKV projection, T4 counted-vmcnt pipeline (R2, proven improvement): BK=32
// slices, 3-deep LDS rotation, prefetch distance 2, raw barriers, vmcnt(8).
//  QKPATH=true  (n0<2048):  swapped MFMA -> qk[m][n] packed 8B along n.
//  QKPATH=false (V blocks): normal MFMA  -> vt[e][m] packed 8B along m.
template<bool QKPATH>
__device__ __forceinline__
void qkv_body(const bf16* __restrict__ A, const bf16* __restrict__ B,
              bf16* __restrict__ qk, bf16* __restrict__ vt,
              bf16* As, bf16* Bs, int m0, int n0)
{
    constexpr int M = 4096;
    const int t = threadIdx.x;
    const int w = t >> 6, lane = t & 63, quad = lane >> 4, ln16 = lane & 15;
    const int wr = (w >> 1) * 64, wc = (w & 1) * 64;
    const int srow = lane >> 2;        // 0..15 within 16-row group
    const int scol = (lane & 3) * 8;   // 0..24 within 32-col slice

    f32x4 acc[4][4] = {};

    // stage slice s (128 rows x 32 cols = 8 KB each of A,B) into buffer s%3.
    auto stage = [&](int s) {
        const int kc = s * 32;
        bf16* Ad = As + (s % 3) * 4096;
        bf16* Bd = Bs + (s % 3) * 4096;
#pragma unroll
        for (int p = 0; p < 2; p++) {
            const int o = w * 2 + p;   // 16-row group 0..7
            GLOBAL_LOAD_LDS16(A + (size_t)(m0 + o * 16 + srow) * 1024 + kc + scol,
                              Ad + o * 512);
            GLOBAL_LOAD_LDS16(B + (size_t)(n0 + o * 16 + srow) * 1024 + kc + scol,
                              Bd + o * 512);
        }
    };

    stage(0);   // 4 VMEM in flight
    stage(1);   // 8 VMEM in flight

    for (int s = 0; s < 32; s++) {
        if (s < 30) {
            stage(s + 2);   // 12 in flight
            asm volatile("s_waitcnt vmcnt(8)" ::: "memory");
        } else if (s == 30) {
            asm volatile("s_waitcnt vmcnt(4)" ::: "memory");
        } else {
            asm volatile("s_waitcnt vmcnt(0)" ::: "memory");
        }
        __builtin_amdgcn_s_barrier();          // slice-s data visible to all
        __builtin_amdgcn_sched_barrier(0);

        const bf16* Ab = As + (s % 3) * 4096;
        const bf16* Bb = Bs + (s % 3) * 4096;
        bf16x8 af[4];
#pragma unroll
        for (int mb = 0; mb < 4; mb++)
            af[mb] = *reinterpret_cast<const bf16x8*>(
                Ab + (wr + mb * 16 + ln16) * 32 + quad * 8);
#pragma unroll
        for (int nb = 0; nb < 4; nb++) {
            bf16x8 bv = *reinterpret_cast<const bf16x8*>(
                Bb + (wc + nb * 16 + ln16) * 32 + quad * 8);
#pragma unroll
            for (int mb = 0; mb < 4; mb++) {
                if constexpr (QKPATH) acc[mb][nb] = MFMA16(bv, af[mb], acc[mb][nb]);
                else                  acc[mb][nb] = MFMA16(af[mb], bv, acc[mb][nb]);
            }
        }

        __builtin_amdgcn_sched_barrier(0);
        __builtin_amdgcn_s_barrier();          // all waves done reading buf[s%3]
    }

    if constexpr (QKPATH) {
#pragma unroll
        for (int mb = 0; mb < 4; mb++)
#pragma unroll
            for (int nb = 0; nb < 4; nb++) {
                size_t idx = (size_t)(m0 + wr + mb * 16 + ln16) * 2048
                           + (n0 + wc + nb * 16 + quad * 4);
                bf16x4 v;
#pragma unroll
                for (int r = 0; r < 4; r++) v[r] = (bf16)acc[mb][nb][r];
                *reinterpret_cast<bf16x4*>(&qk[idx]) = v;
            }
    } else {
#pragma unroll
        for (int mb = 0; mb < 4; mb++)
#pragma unroll
            for (int nb = 0; nb < 4; nb++) {
                const int e = n0 - 2048 + wc + nb * 16 + ln16;
                size_t idx = (size_t)e * M + (m0 + wr + mb * 16 + quad * 4);
                bf16x4 v;
#pragma unroll
                for (int r = 0; r < 4; r++) v[r] = (bf16)acc[mb][nb][r];
                *reinterpret_cast<bf16x4*>(&vt[idx]) = v;
            }
    }
}

__global__ __launch_bounds__(256)
void gemm_qkv(const bf16* __restrict__ A, const bf16* __restrict__ B,
              bf16* __restrict__ qk, bf16* __restrict__ vt)
{
    __shared__ __align__(16) bf16 As[12288];  // 3 rotating [128][32] buffers
    __shared__ __align__(16) bf16 Bs[12288];
    const int m0 = blockIdx.y * 128, n0 = blockIdx.x * 128;
    if (n0 < 2048) qkv_body<true >(A, B, qk, vt, As, Bs, m0, n0);
    else           qkv_body<false>(A, B, qk, vt, As, Bs, m0, n0);
}

// ---------------------------------------------------------------------------
// Out projection v6: 128x64 tiles (panel traffic 268->128 MB redundant reads),
// BK=64 steps (16 MFMA/wave between barriers, 16 steps), 3-deep counted-vmcnt
// rotation (6 VMEM/stage -> steady vmcnt(12)), XCD-chunk swizzle: each XCD's
// 64 blocks = 4 m-tiles x all 16 n-tiles -> working set A 1MB + B 2MB <= L2.
// 72 KB LDS -> 2 blocks/CU = exactly the 512-block grid's demand.
__global__ __launch_bounds__(256)
void gemm_out(const bf16* __restrict__ A, const bf16* __restrict__ Bw,
              float* __restrict__ C)
{
    __shared__ __align__(16) bf16 As[24576];  // 3 x [2 k-halves][128][32]
    __shared__ __align__(16) bf16 Bs[12288];  // 3 x [2 k-halves][ 64][32]

    const int t = threadIdx.x;
    const int w = t >> 6, lane = t & 63, quad = lane >> 4, ln16 = lane & 15;

    // bijective XCD swizzle (512 % 8 == 0): XCD c -> m-tiles [4c,4c+4) x n all
    const int bid = blockIdx.x;
    const int xcd = bid & 7, idx = bid >> 3;
    const int m0 = (xcd * 4 + (idx >> 4)) * 128;
    const int n0 = (idx & 15) * 64;

    const int wr = (w >> 1) * 64, wc = (w & 1) * 32;
    const int srow = lane >> 2;
    const int scol = (lane & 3) * 8;

    f32x4 acc[4][2] = {};

    // stage slice s (A 128x64 = 16 KB, B 64x64 = 8 KB) into buffer s%3.
    // per wave: 4 A-ops + 2 B-ops = 6 VMEM instructions.
    auto stage = [&](int s) {
        const int k0 = s * 64;
        bf16* Ad = As + (s % 3) * 8192;
        bf16* Bd = Bs + (s % 3) * 4096;
#pragma unroll
        for (int p = 0; p < 4; p++) {
            const int i = w * 4 + p;           // 16 ops: h = k-half, o = row grp
            const int h = i >> 3, o = i & 7;
            GLOBAL_LOAD_LDS16(A + (size_t)(m0 + o * 16 + srow) * 1024 + k0 + h * 32 + scol,
                              Ad + h * 4096 + o * 512);
        }
#pragma unroll
        for (int p = 0; p < 2; p++) {
            const int i = w * 2 + p;           // 8 ops
            const int h = i >> 2, o = i & 3;
            GLOBAL_LOAD_LDS16(Bw + (size_t)(n0 + o * 16 + srow) * 1024 + k0 + h * 32 + scol,
                              Bd + h * 2048 + o * 512);
        }
    };

    stage(0);   // 6 in flight
    stage(1);   // 12 in flight

    for (int s = 0; s < 16; s++) {
        if (s < 14) {
            stage(s + 2);   // 18 in flight; counted wait retires slice s only
            asm volatile("s_waitcnt vmcnt(12)" ::: "memory");
        } else if (s == 14) {
            asm volatile("s_waitcnt vmcnt(6)" ::: "memory");
        } else {
            asm volatile("s_waitcnt vmcnt(0)" ::: "memory");
        }
        __builtin_amdgcn_s_barrier();
        __builtin_amdgcn_sched_barrier(0);

        const bf16* Ab = As + (s % 3) * 8192;
        const bf16* Bb = Bs + (s % 3) * 4096;
#pragma unroll
        for (int kki = 0; kki < 2; kki++) {
            bf16x8 af[4];
#pragma unroll
            for (int mb = 0; mb < 4; mb++)
                af[mb] = *reinterpret_cast<const bf16x8*>(
                    Ab + kki * 4096 + (wr + mb * 16 + ln16) * 32 + quad * 8);
#pragma unroll
            for (int nb = 0; nb < 2; nb++) {
                bf16x8 bv = *reinterpret_cast<const bf16x8*>(
                    Bb + kki * 2048 + (wc + nb * 16 + ln16) * 32 + quad * 8);
#pragma unroll
                for (int mb = 0; mb < 4; mb++)
                    acc[mb][nb] = MFMA16(bv, af[mb], acc[mb][nb]);  // swapped
            }
        }

        __builtin_amdgcn_sched_barrier(0);
        __builtin_amdgcn_s_barrier();
    }

    // lane: m = ...+ln16 fixed, n = ...+quad*4 + r -> packed f32x4 stores
#pragma unroll
    for (int mb = 0; mb < 4; mb++)
#pragma unroll
        for (int nb = 0; nb < 2; nb++) {
            size_t idx = (size_t)(m0 + wr + mb * 16 + ln16) * 1024
                       + (n0 + wc + nb * 16 + quad * 4);
            *reinterpret_cast<f32x4*>(&C[idx]) = acc[mb][nb];
        }
}

// ---------------------------------------------------------------------------
// Fused causal flash attention v6 (R7, proven 47.4 us) — unchanged.
__global__ __launch_bounds__(256)
void attn_flash6(const bf16* __restrict__ qk, const bf16* __restrict__ vt,
                 bf16* __restrict__ z)
{
    constexpr int Tn = 2048, Dm = 1024, QLD = 2048, VLD = 4096;
    constexpr int KP = 72;
    __shared__ __align__(16) bf16 Ks[64 * KP];
    __shared__ __align__(16) bf16 VTs[64 * KP];
    __shared__ __align__(16) bf16 Ps[64 * KP];

    const int t = threadIdx.x;
    const int w = t >> 6, lane = t & 63, quad = lane >> 4, ln16 = lane & 15;
    const int q = blockIdx.x >> 5, g = blockIdx.x & 31;
    const int s4 = q >> 3, q0i = q & 7;
    const int j = (s4 == 0) ? q0i : (s4 == 1) ? (15 - q0i)
                : (s4 == 2) ? (16 + q0i) : (31 - q0i);
    const int b = g >> 4, h = g & 15;
    const int q0 = j * 64;

    const bf16* Qb = qk + (size_t)b * Tn * QLD + h * 64;
    const bf16* Kb = Qb + 1024;
    const bf16* Vb = vt + (size_t)(h * 64) * VLD + b * Tn;

    constexpr float C2 = 0.125f * 1.44269504089f;
    bf16x8 qf[2];
#pragma unroll
    for (int kki = 0; kki < 2; kki++) {
        bf16x8 qv = *reinterpret_cast<const bf16x8*>(
            Qb + (size_t)(q0 + w * 16 + ln16) * QLD + kki * 32 + quad * 8);
#pragma unroll
        for (int u = 0; u < 8; u++) qf[kki][u] = (bf16)((float)qv[u] * C2);
    }

    bf16x8 vones;
#pragma unroll
    for (int u = 0; u < 8; u++) vones[u] = (bf16)1.0f;

    const int sr = t >> 3;
    const int sseg = (t & 7) * 8;

    bf16x8 kreg[2], vreg[2];
#pragma unroll
    for (int p = 0; p < 2; p++) {
        kreg[p] = *reinterpret_cast<const bf16x8*>(Kb + (size_t)(sr + p * 32) * QLD + sseg);
        vreg[p] = *reinterpret_cast<const bf16x8*>(Vb + (size_t)(sr + p * 32) * VLD + sseg);
    }

    f32x4 accO[5] = {};
    const int qloc = w * 16 + ln16;

    for (int kt = 0; kt <= j; kt++) {
        __syncthreads();
#pragma unroll
        for (int p = 0; p < 2; p++) {
            *reinterpret_cast<bf16x8*>(&Ks[(sr + p * 32) * KP + sseg]) = kreg[p];
            *reinterpret_cast<bf16x8*>(&VTs[(sr + p * 32) * KP + sseg]) = vreg[p];
        }
        __syncthreads();

        if (kt < j) {
            const int k1 = (kt + 1) * 64;
#pragma unroll
            for (int p = 0; p < 2; p++) {
                kreg[p] = *reinterpret_cast<const bf16x8*>(
                    Kb + (size_t)(k1 + sr + p * 32) * QLD + sseg);
                vreg[p] = *reinterpret_cast<const bf16x8*>(
                    Vb + (size_t)(sr + p * 32) * VLD + k1 + sseg);
            }
        }

        f32x4 aS[4] = {};
#pragma unroll
        for (int kki = 0; kki < 2; kki++)
#pragma unroll
            for (int nb = 0; nb < 4; nb++) {
                bf16x8 kb = *reinterpret_cast<const bf16x8*>(
                    &Ks[(nb * 16 + ln16) * KP + kki * 32 + quad * 8]);
                aS[nb] = MFMA16(kb, qf[kki], aS[nb]);
            }

        if (kt == j) {
#pragma unroll
            for (int nb = 0; nb < 4; nb++) {
                bf16x4 pv;
#pragma unroll
                for (int r = 0; r < 4; r++) {
                    float p = __builtin_amdgcn_exp2f(aS[nb][r]);
                    if ((nb * 16 + quad * 4 + r) > qloc) p = 0.f;
                    pv[r] = (bf16)p;
                }
                *reinterpret_cast<bf16x4*>(&Ps[qloc * KP + nb * 16 + quad * 4]) = pv;
            }
        } else {
#pragma unroll
            for (int nb = 0; nb < 4; nb++) {
                bf16x4 pv;
#pragma unroll
                for (int r = 0; r < 4; r++)
                    pv[r] = (bf16)__builtin_amdgcn_exp2f(aS[nb][r]);
                *reinterpret_cast<bf16x4*>(&Ps[qloc * KP + nb * 16 + quad * 4]) = pv;
            }
        }
        asm volatile("s_waitcnt lgkmcnt(0)" ::: "memory");

#pragma unroll
        for (int kki = 0; kki < 2; kki++) {
            bf16x8 pa = *reinterpret_cast<const bf16x8*>(
                &Ps[qloc * KP + kki * 32 + quad * 8]);
#pragma unroll
            for (int nb = 0; nb < 4; nb++) {
                bf16x8 vb = *reinterpret_cast<const bf16x8*>(
                    &VTs[(nb * 16 + ln16) * KP + kki * 32 + quad * 8]);
                accO[nb] = MFMA16(vb, pa, accO[nb]);
            }
            accO[4] = MFMA16(vones, pa, accO[4]);
        }
    }

    const float linv = 1.0f / accO[4][0];
    const size_t zr = ((size_t)b * Tn + q0 + qloc) * Dm + h * 64;
#pragma unroll
    for (int nb = 0; nb < 4; nb++) {
        bf16x4 v;
#pragma unroll
        for (int r = 0; r < 4; r++) v[r] = (bf16)(accO[nb][r] * linv);
        *reinterpret_cast<bf16x4*>(z + zr + nb * 16 + quad * 4) = v;
    }
}

// ---------------------------------------------------------------------------
extern "C" void kernel_launch(void* const* d_in, const int* in_sizes, int n_in,
                              void* d_out, int out_size, void* d_ws, size_t ws_size,
                              hipStream_t stream)
{
    constexpr int B = 2, T = 2048, D = 1024;
    constexpr int M = B * T;  // 4096

    const float* X    = (const float*)d_in[0];
    const float* Wqkv = (const float*)d_in[1];
    const float* Wout = (const float*)d_in[2];
    float* out = (float*)d_out;

    // ws: qk [M][2048] 16 MiB | vt [1024][M] 8 MiB | z [M][1024] 8 MiB
    bf16* qk  = (bf16*)d_ws;
    bf16* vt  = qk + (size_t)M * 2048;
    bf16* zbf = vt + (size_t)1024 * M;
    // d_out as scratch until gemm_out writes it (Xbf 8 MiB + Wqkvbf 6 MiB <= 16)
    bf16* Xbf    = (bf16*)d_out;
    bf16* Wqkvbf = Xbf + (size_t)M * D;
    // Woutbf reuses the vt region -- vt is dead after attn_flash6
    bf16* Woutbf = vt;

    dim3 blk(256);
    const int n1 = M * D / 8, n2 = 3 * D * D / 8;
    cvt2<<<(n1 + n2 + 255) / 256, blk, 0, stream>>>(X, Wqkv, Xbf, n1, n1 + n2);

    gemm_qkv<<<dim3(24, 32), blk, 0, stream>>>(Xbf, Wqkvbf, qk, vt);

    attn_flash6<<<dim3(1024), blk, 0, stream>>>(qk, vt, zbf);

    const int n3 = D * D / 8;
    cvt2<<<(n3 + 255) / 256, blk, 0, stream>>>(Wout, Wout, Woutbf, n3, n3);

    gemm_out<<<dim3(512), blk, 0, stream>>>(zbf, Woutbf, out);
}

// Round 10
// 175.489 us; speedup vs baseline: 1.0634x; 1.0001x over previous
//
#include <hip/hip_runtime.h>
#include <hip/hip_bf16.h>

typedef __bf16 bf16;
typedef __bf16 bf16x4 __attribute__((ext_vector_type(4)));
typedef __bf16 bf16x8 __attribute__((ext_vector_type(8)));
typedef float  f32x4 __attribute__((ext_vector_type(4)));

#define MFMA16(a, b, c) __builtin_amdgcn_mfma_f32_16x16x32_bf16((a), (b), (c), 0, 0, 0)

// async 16B/lane global->LDS (m97). LDS dst = uniform base + lane*16.
#define GLOBAL_LOAD_LDS16(gp, lp)                                                     \
    __builtin_amdgcn_global_load_lds(                                                 \
        (const __attribute__((address_space(1))) void*)(gp),                          \
        (__attribute__((address_space(3))) void*)(lp), 16, 0, 0)

// ---------------------------------------------------------------------------
// fp32 -> bf16, two sources into one contiguous dst (8 elems/thread)
__global__ __launch_bounds__(256)
void cvt2(const float* __restrict__ s1, const float* __restrict__ s2,
          bf16* __restrict__ dst, int n1, int ntot)
{
    int i = blockIdx.x * 256 + threadIdx.x;
    if (i >= ntot) return;
    const float* s = (i < n1) ? s1 + (size_t)i * 8 : s2 + (size_t)(i - n1) * 8;
    f32x4 a = *reinterpret_cast<const f32x4*>(s);
    f32x4 b = *reinterpret_cast<const f32x4*>(s + 4);
    bf16x8 r;
#pragma unroll
    for (int u = 0; u < 4; u++) { r[u] = (bf16)a[u]; r[u + 4] = (bf16)b[u]; }
    *reinterpret_cast<bf16x8*>(dst + (size_t)i * 8) = r;
}

// ---------------------------------------------------------------------------
// QKV projection, T4 counted-vmcnt pipeline (R2) + T2 both-sides swizzle (R5):
// [rows][32] bf16 tiles have row stride 64B -> af/bv reads put 16 lanes on 2
// of 8 bank slots (8-way, ~2.9x; SQ_LDS_BANK_CONFLICT=3.1M). gload_lds can't
// pad (writes linearly), so: pre-swizzle the GLOBAL source col-slot by
// (lane&3)^((lane>>3)&3) (XOR within-row 16B slot with (row>>1)&3, involutive)
// and XOR the read slot quad^((ln16>>1)&3). Read becomes 2-way = free (m136).
//  QKPATH=true  (n0<2048):  swapped MFMA -> qk[m][n] packed 8B along n.
//  QKPATH=false (V blocks): normal MFMA  -> vt[e][m] packed 8B along m.
template<bool QKPATH>
__device__ __forceinline__
void qkv_body(const bf16* __restrict__ A, const bf16* __restrict__ B,
              bf16* __restrict__ qk, bf16* __restrict__ vt,
              bf16* As, bf16* Bs, int m0, int n0)
{
    constexpr int M = 4096;
    const int t = threadIdx.x;
    const int w = t >> 6, lane = t & 63, quad = lane >> 4, ln16 = lane & 15;
    const int wr = (w >> 1) * 64, wc = (w & 1) * 64;
    const int srow = lane >> 2;        // 0..15 within 16-row group
    // pre-swizzled global col-slot: (lane&3) ^ ((srow>>1)&3), 8 bf16 per slot
    const int scolsw = (((lane & 3) ^ ((lane >> 3) & 3)) * 8);
    // swizzled LDS read slot (inverse of the same involution)
    const int qsw = quad ^ ((ln16 >> 1) & 3);

    f32x4 acc[4][4] = {};

    // stage slice s (128 rows x 32 cols = 8 KB each of A,B) into buffer s%3.
    auto stage = [&](int s) {
        const int kc = s * 32;
        bf16* Ad = As + (s % 3) * 4096;
        bf16* Bd = Bs + (s % 3) * 4096;
#pragma unroll
        for (int p = 0; p < 2; p++) {
            const int o = w * 2 + p;   // 16-row group 0..7
            GLOBAL_LOAD_LDS16(A + (size_t)(m0 + o * 16 + srow) * 1024 + kc + scolsw,
                              Ad + o * 512);
            GLOBAL_LOAD_LDS16(B + (size_t)(n0 + o * 16 + srow) * 1024 + kc + scolsw,
                              Bd + o * 512);
        }
    };

    stage(0);   // 4 VMEM in flight
    stage(1);   // 8 VMEM in flight

    for (int s = 0; s < 32; s++) {
        if (s < 30) {
            stage(s + 2);   // 12 in flight
            asm volatile("s_waitcnt vmcnt(8)" ::: "memory");
        } else if (s == 30) {
            asm volatile("s_waitcnt vmcnt(4)" ::: "memory");
        } else {
            asm volatile("s_waitcnt vmcnt(0)" ::: "memory");
        }
        __builtin_amdgcn_s_barrier();          // slice-s data visible to all
        __builtin_amdgcn_sched_barrier(0);

        const bf16* Ab = As + (s % 3) * 4096;
        const bf16* Bb = Bs + (s % 3) * 4096;
        bf16x8 af[4];
#pragma unroll
        for (int mb = 0; mb < 4; mb++)
            af[mb] = *reinterpret_cast<const bf16x8*>(
                Ab + (wr + mb * 16 + ln16) * 32 + qsw * 8);
#pragma unroll
        for (int nb = 0; nb < 4; nb++) {
            bf16x8 bv = *reinterpret_cast<const bf16x8*>(
                Bb + (wc + nb * 16 + ln16) * 32 + qsw * 8);
#pragma unroll
            for (int mb = 0; mb < 4; mb++) {
                if constexpr (QKPATH) acc[mb][nb] = MFMA16(bv, af[mb], acc[mb][nb]);
                else                  acc[mb][nb] = MFMA16(af[mb], bv, acc[mb][nb]);
            }
        }

        __builtin_amdgcn_sched_barrier(0);
        __builtin_amdgcn_s_barrier();          // all waves done reading buf[s%3]
    }

    if constexpr (QKPATH) {
#pragma unroll
        for (int mb = 0; mb < 4; mb++)
#pragma unroll
            for (int nb = 0; nb < 4; nb++) {
                size_t idx = (size_t)(m0 + wr + mb * 16 + ln16) * 2048
                           + (n0 + wc + nb * 16 + quad * 4);
                bf16x4 v;
#pragma unroll
                for (int r = 0; r < 4; r++) v[r] = (bf16)acc[mb][nb][r];
                *reinterpret_cast<bf16x4*>(&qk[idx]) = v;
            }
    } else {
#pragma unroll
        for (int mb = 0; mb < 4; mb++)
#pragma unroll
            for (int nb = 0; nb < 4; nb++) {
                const int e = n0 - 2048 + wc + nb * 16 + ln16;
                size_t idx = (size_t)e * M + (m0 + wr + mb * 16 + quad * 4);
                bf16x4 v;
#pragma unroll
                for (int r = 0; r < 4; r++) v[r] = (bf16)acc[mb][nb][r];
                *reinterpret_cast<bf16x4*>(&vt[idx]) = v;
            }
    }
}

__global__ __launch_bounds__(256)
void gemm_qkv(const bf16* __restrict__ A, const bf16* __restrict__ B,
              bf16* __restrict__ qk, bf16* __restrict__ vt)
{
    __shared__ __align__(16) bf16 As[12288];  // 3 rotating [128][32] buffers
    __shared__ __align__(16) bf16 Bs[12288];
    const int m0 = blockIdx.y * 128, n0 = blockIdx.x * 128;
    if (n0 < 2048) qkv_body<true >(A, B, qk, vt, As, Bs, m0, n0);
    else           qkv_body<false>(A, B, qk, vt, As, Bs, m0, n0);
}

// ---------------------------------------------------------------------------
// Out projection v7: R4's 128x64/BK=64/counted-vmcnt/XCD-chunk structure
// + the same T2 both-sides swizzle on A and B staging/reads.
__global__ __launch_bounds__(256)
void gemm_out(const bf16* __restrict__ A, const bf16* __restrict__ Bw,
              float* __restrict__ C)
{
    __shared__ __align__(16) bf16 As[24576];  // 3 x [2 k-halves][128][32]
    __shared__ __align__(16) bf16 Bs[12288];  // 3 x [2 k-halves][ 64][32]

    const int t = threadIdx.x;
    const int w = t >> 6, lane = t & 63, quad = lane >> 4, ln16 = lane & 15;

    // bijective XCD swizzle (512 % 8 == 0): XCD c -> m-tiles [4c,4c+4) x n all
    const int bid = blockIdx.x;
    const int xcd = bid & 7, idx = bid >> 3;
    const int m0 = (xcd * 4 + (idx >> 4)) * 128;
    const int n0 = (idx & 15) * 64;

    const int wr = (w >> 1) * 64, wc = (w & 1) * 32;
    const int srow = lane >> 2;
    const int scolsw = (((lane & 3) ^ ((lane >> 3) & 3)) * 8);
    const int qsw = quad ^ ((ln16 >> 1) & 3);

    f32x4 acc[4][2] = {};

    // stage slice s (A 128x64 = 16 KB, B 64x64 = 8 KB) into buffer s%3.
    // per wave: 4 A-ops + 2 B-ops = 6 VMEM instructions.
    auto stage = [&](int s) {
        const int k0 = s * 64;
        bf16* Ad = As + (s % 3) * 8192;
        bf16* Bd = Bs + (s % 3) * 4096;
#pragma unroll
        for (int p = 0; p < 4; p++) {
            const int i = w * 4 + p;           // 16 ops: h = k-half, o = row grp
            const int h = i >> 3, o = i & 7;
            GLOBAL_LOAD_LDS16(A + (size_t)(m0 + o * 16 + srow) * 1024 + k0 + h * 32 + scolsw,
                              Ad + h * 4096 + o * 512);
        }
#pragma unroll
        for (int p = 0; p < 2; p++) {
            const int i = w * 2 + p;           // 8 ops
            const int h = i >> 2, o = i & 3;
            GLOBAL_LOAD_LDS16(Bw + (size_t)(n0 + o * 16 + srow) * 1024 + k0 + h * 32 + scolsw,
                              Bd + h * 2048 + o * 512);
        }
    };

    stage(0);   // 6 in flight
    stage(1);   // 12 in flight

    for (int s = 0; s < 16; s++) {
        if (s < 14) {
            stage(s + 2);   // 18 in flight; counted wait retires slice s only
            asm volatile("s_waitcnt vmcnt(12)" ::: "memory");
        } else if (s == 14) {
            asm volatile("s_waitcnt vmcnt(6)" ::: "memory");
        } else {
            asm volatile("s_waitcnt vmcnt(0)" ::: "memory");
        }
        __builtin_amdgcn_s_barrier();
        __builtin_amdgcn_sched_barrier(0);

        const bf16* Ab = As + (s % 3) * 8192;
        const bf16* Bb = Bs + (s % 3) * 4096;
#pragma unroll
        for (int kki = 0; kki < 2; kki++) {
            bf16x8 af[4];
#pragma unroll
            for (int mb = 0; mb < 4; mb++)
                af[mb] = *reinterpret_cast<const bf16x8*>(
                    Ab + kki * 4096 + (wr + mb * 16 + ln16) * 32 + qsw * 8);
#pragma unroll
            for (int nb = 0; nb < 2; nb++) {
                bf16x8 bv = *reinterpret_cast<const bf16x8*>(
                    Bb + kki * 2048 + (wc + nb * 16 + ln16) * 32 + qsw * 8);
#pragma unroll
                for (int mb = 0; mb < 4; mb++)
                    acc[mb][nb] = MFMA16(bv, af[mb], acc[mb][nb]);  // swapped
            }
        }

        __builtin_amdgcn_sched_barrier(0);
        __builtin_amdgcn_s_barrier();
    }

    // lane: m = ...+ln16 fixed, n = ...+quad*4 + r -> packed f32x4 stores
#pragma unroll
    for (int mb = 0; mb < 4; mb++)
#pragma unroll
        for (int nb = 0; nb < 2; nb++) {
            size_t idx = (size_t)(m0 + wr + mb * 16 + ln16) * 1024
                       + (n0 + wc + nb * 16 + quad * 4);
            *reinterpret_cast<f32x4*>(&C[idx]) = acc[mb][nb];
        }
}

// ---------------------------------------------------------------------------
// Fused causal flash attention v6 (R7, proven 47.4 us) — unchanged.
__global__ __launch_bounds__(256)
void attn_flash6(const bf16* __restrict__ qk, const bf16* __restrict__ vt,
                 bf16* __restrict__ z)
{
    constexpr int Tn = 2048, Dm = 1024, QLD = 2048, VLD = 4096;
    constexpr int KP = 72;
    __shared__ __align__(16) bf16 Ks[64 * KP];
    __shared__ __align__(16) bf16 VTs[64 * KP];
    __shared__ __align__(16) bf16 Ps[64 * KP];

    const int t = threadIdx.x;
    const int w = t >> 6, lane = t & 63, quad = lane >> 4, ln16 = lane & 15;
    const int q = blockIdx.x >> 5, g = blockIdx.x & 31;
    const int s4 = q >> 3, q0i = q & 7;
    const int j = (s4 == 0) ? q0i : (s4 == 1) ? (15 - q0i)
                : (s4 == 2) ? (16 + q0i) : (31 - q0i);
    const int b = g >> 4, h = g & 15;
    const int q0 = j * 64;

    const bf16* Qb = qk + (size_t)b * Tn * QLD + h * 64;
    const bf16* Kb = Qb + 1024;
    const bf16* Vb = vt + (size_t)(h * 64) * VLD + b * Tn;

    constexpr float C2 = 0.125f * 1.44269504089f;
    bf16x8 qf[2];
#pragma unroll
    for (int kki = 0; kki < 2; kki++) {
        bf16x8 qv = *reinterpret_cast<const bf16x8*>(
            Qb + (size_t)(q0 + w * 16 + ln16) * QLD + kki * 32 + quad * 8);
#pragma unroll
        for (int u = 0; u < 8; u++) qf[kki][u] = (bf16)((float)qv[u] * C2);
    }

    bf16x8 vones;
#pragma unroll
    for (int u = 0; u < 8; u++) vones[u] = (bf16)1.0f;

    const int sr = t >> 3;
    const int sseg = (t & 7) * 8;

    bf16x8 kreg[2], vreg[2];
#pragma unroll
    for (int p = 0; p < 2; p++) {
        kreg[p] = *reinterpret_cast<const bf16x8*>(Kb + (size_t)(sr + p * 32) * QLD + sseg);
        vreg[p] = *reinterpret_cast<const bf16x8*>(Vb + (size_t)(sr + p * 32) * VLD + sseg);
    }

    f32x4 accO[5] = {};
    const int qloc = w * 16 + ln16;

    for (int kt = 0; kt <= j; kt++) {
        __syncthreads();
#pragma unroll
        for (int p = 0; p < 2; p++) {
            *reinterpret_cast<bf16x8*>(&Ks[(sr + p * 32) * KP + sseg]) = kreg[p];
            *reinterpret_cast<bf16x8*>(&VTs[(sr + p * 32) * KP + sseg]) = vreg[p];
        }
        __syncthreads();

        if (kt < j) {
            const int k1 = (kt + 1) * 64;
#pragma unroll
            for (int p = 0; p < 2; p++) {
                kreg[p] = *reinterpret_cast<const bf16x8*>(
                    Kb + (size_t)(k1 + sr + p * 32) * QLD + sseg);
                vreg[p] = *reinterpret_cast<const bf16x8*>(
                    Vb + (size_t)(sr + p * 32) * VLD + k1 + sseg);
            }
        }

        f32x4 aS[4] = {};
#pragma unroll
        for (int kki = 0; kki < 2; kki++)
#pragma unroll
            for (int nb = 0; nb < 4; nb++) {
                bf16x8 kb = *reinterpret_cast<const bf16x8*>(
                    &Ks[(nb * 16 + ln16) * KP + kki * 32 + quad * 8]);
                aS[nb] = MFMA16(kb, qf[kki], aS[nb]);
            }

        if (kt == j) {
#pragma unroll
            for (int nb = 0; nb < 4; nb++) {
                bf16x4 pv;
#pragma unroll
                for (int r = 0; r < 4; r++) {
                    float p = __builtin_amdgcn_exp2f(aS[nb][r]);
                    if ((nb * 16 + quad * 4 + r) > qloc) p = 0.f;
                    pv[r] = (bf16)p;
                }
                *reinterpret_cast<bf16x4*>(&Ps[qloc * KP + nb * 16 + quad * 4]) = pv;
            }
        } else {
#pragma unroll
            for (int nb = 0; nb < 4; nb++) {
                bf16x4 pv;
#pragma unroll
                for (int r = 0; r < 4; r++)
                    pv[r] = (bf16)__builtin_amdgcn_exp2f(aS[nb][r]);
                *reinterpret_cast<bf16x4*>(&Ps[qloc * KP + nb * 16 + quad * 4]) = pv;
            }
        }
        asm volatile("s_waitcnt lgkmcnt(0)" ::: "memory");

#pragma unroll
        for (int kki = 0; kki < 2; kki++) {
            bf16x8 pa = *reinterpret_cast<const bf16x8*>(
                &Ps[qloc * KP + kki * 32 + quad * 8]);
#pragma unroll
            for (int nb = 0; nb < 4; nb++) {
                bf16x8 vb = *reinterpret_cast<const bf16x8*>(
                    &VTs[(nb * 16 + ln16) * KP + kki * 32 + quad * 8]);
                accO[nb] = MFMA16(vb, pa, accO[nb]);
            }
            accO[4] = MFMA16(vones, pa, accO[4]);
        }
    }

    const float linv = 1.0f / accO[4][0];
    const size_t zr = ((size_t)b * Tn + q0 + qloc) * Dm + h * 64;
#pragma unroll
    for (int nb = 0; nb < 4; nb++) {
        bf16x4 v;
#pragma unroll
        for (int r = 0; r < 4; r++) v[r] = (bf16)(accO[nb][r] * linv);
        *reinterpret_cast<bf16x4*>(z + zr + nb * 16 + quad * 4) = v;
    }
}

// ---------------------------------------------------------------------------
extern "C" void kernel_launch(void* const* d_in, const int* in_sizes, int n_in,
                              void* d_out, int out_size, void* d_ws, size_t ws_size,
                              hipStream_t stream)
{
    constexpr int B = 2, T = 2048, D = 1024;
    constexpr int M = B * T;  // 4096

    const float* X    = (const float*)d_in[0];
    const float* Wqkv = (const float*)d_in[1];
    const float* Wout = (const float*)d_in[2];
    float* out = (float*)d_out;

    // ws: qk [M][2048] 16 MiB | vt [1024][M] 8 MiB | z [M][1024] 8 MiB
    bf16* qk  = (bf16*)d_ws;
    bf16* vt  = qk + (size_t)M * 2048;
    bf16* zbf = vt + (size_t)1024 * M;
    // d_out as scratch until gemm_out writes it (Xbf 8 MiB + Wqkvbf 6 MiB <= 16)
    bf16* Xbf    = (bf16*)d_out;
    bf16* Wqkvbf = Xbf + (size_t)M * D;
    // Woutbf reuses the vt region -- vt is dead after attn_flash6
    bf16* Woutbf = vt;

    dim3 blk(256);
    const int n1 = M * D / 8, n2 = 3 * D * D / 8;
    cvt2<<<(n1 + n2 + 255) / 256, blk, 0, stream>>>(X, Wqkv, Xbf, n1, n1 + n2);

    gemm_qkv<<<dim3(24, 32), blk, 0, stream>>>(Xbf, Wqkvbf, qk, vt);

    attn_flash6<<<dim3(1024), blk, 0, stream>>>(qk, vt, zbf);

    const int n3 = D * D / 8;
    cvt2<<<(n3 + 255) / 256, blk, 0, stream>>>(Wout, Wout, Woutbf, n3, n3);

    gemm_out<<<dim3(512), blk, 0, stream>>>(zbf, Woutbf, out);
}

// Round 11
// 174.846 us; speedup vs baseline: 1.0673x; 1.0037x over previous
//
#include <hip/hip_runtime.h>
#include <hip/hip_bf16.h>

typedef __bf16 bf16;
typedef __bf16 bf16x4 __attribute__((ext_vector_type(4)));
typedef __bf16 bf16x8 __attribute__((ext_vector_type(8)));
typedef float  f32x4 __attribute__((ext_vector_type(4)));

#define MFMA16(a, b, c) __builtin_amdgcn_mfma_f32_16x16x32_bf16((a), (b), (c), 0, 0, 0)

// async 16B/lane global->LDS (m97). LDS dst = uniform base + lane*16.
#define GLOBAL_LOAD_LDS16(gp, lp)                                                     \
    __builtin_amdgcn_global_load_lds(                                                 \
        (const __attribute__((address_space(1))) void*)(gp),                          \
        (__attribute__((address_space(3))) void*)(lp), 16, 0, 0)

// ---------------------------------------------------------------------------
// fp32 -> bf16, three sources in ONE launch (R11: fuses the old two cvt2
// dispatches; Wout conversion no longer sits serially between attn and
// gemm_out). s1,s2 -> contiguous d12; s3 -> d3.
__global__ __launch_bounds__(256)
void cvt3(const float* __restrict__ s1, const float* __restrict__ s2,
          const float* __restrict__ s3, bf16* __restrict__ d12,
          bf16* __restrict__ d3, int n1, int n12, int ntot)
{
    int i = blockIdx.x * 256 + threadIdx.x;
    if (i >= ntot) return;
    const float* s;
    bf16* d;
    if (i < n12) {
        s = (i < n1) ? s1 + (size_t)i * 8 : s2 + (size_t)(i - n1) * 8;
        d = d12 + (size_t)i * 8;
    } else {
        s = s3 + (size_t)(i - n12) * 8;
        d = d3 + (size_t)(i - n12) * 8;
    }
    f32x4 a = *reinterpret_cast<const f32x4*>(s);
    f32x4 b = *reinterpret_cast<const f32x4*>(s + 4);
    bf16x8 r;
#pragma unroll
    for (int u = 0; u < 4; u++) { r[u] = (bf16)a[u]; r[u + 4] = (bf16)b[u]; }
    *reinterpret_cast<bf16x8*>(d) = r;
}

// ---------------------------------------------------------------------------
// QKV projection, T4 counted-vmcnt pipeline (R2) + source/read swizzle (R10,
// measured neutral -- kept, verified correct; SQ_LDS_BANK_CONFLICT on these
// [rows][32] b128 reads is wide-op phasing at the 8-lane/4-bank throughput
// floor, not serialization).
//  QKPATH=true  (n0<2048):  swapped MFMA -> qk[m][n] packed 8B along n.
//  QKPATH=false (V blocks): normal MFMA  -> vt[e][m] packed 8B along m.
template<bool QKPATH>
__device__ __forceinline__
void qkv_body(const bf16* __restrict__ A, const bf16* __restrict__ B,
              bf16* __restrict__ qk, bf16* __restrict__ vt,
              bf16* As, bf16* Bs, int m0, int n0)
{
    constexpr int M = 4096;
    const int t = threadIdx.x;
    const int w = t >> 6, lane = t & 63, quad = lane >> 4, ln16 = lane & 15;
    const int wr = (w >> 1) * 64, wc = (w & 1) * 64;
    const int srow = lane >> 2;        // 0..15 within 16-row group
    const int scolsw = (((lane & 3) ^ ((lane >> 3) & 3)) * 8);
    const int qsw = quad ^ ((ln16 >> 1) & 3);

    f32x4 acc[4][4] = {};

    // stage slice s (128 rows x 32 cols = 8 KB each of A,B) into buffer s%3.
    auto stage = [&](int s) {
        const int kc = s * 32;
        bf16* Ad = As + (s % 3) * 4096;
        bf16* Bd = Bs + (s % 3) * 4096;
#pragma unroll
        for (int p = 0; p < 2; p++) {
            const int o = w * 2 + p;   // 16-row group 0..7
            GLOBAL_LOAD_LDS16(A + (size_t)(m0 + o * 16 + srow) * 1024 + kc + scolsw,
                              Ad + o * 512);
            GLOBAL_LOAD_LDS16(B + (size_t)(n0 + o * 16 + srow) * 1024 + kc + scolsw,
                              Bd + o * 512);
        }
    };

    stage(0);   // 4 VMEM in flight
    stage(1);   // 8 VMEM in flight

    for (int s = 0; s < 32; s++) {
        if (s < 30) {
            stage(s + 2);   // 12 in flight
            asm volatile("s_waitcnt vmcnt(8)" ::: "memory");
        } else if (s == 30) {
            asm volatile("s_waitcnt vmcnt(4)" ::: "memory");
        } else {
            asm volatile("s_waitcnt vmcnt(0)" ::: "memory");
        }
        __builtin_amdgcn_s_barrier();          // slice-s data visible to all
        __builtin_amdgcn_sched_barrier(0);

        const bf16* Ab = As + (s % 3) * 4096;
        const bf16* Bb = Bs + (s % 3) * 4096;
        bf16x8 af[4];
#pragma unroll
        for (int mb = 0; mb < 4; mb++)
            af[mb] = *reinterpret_cast<const bf16x8*>(
                Ab + (wr + mb * 16 + ln16) * 32 + qsw * 8);
#pragma unroll
        for (int nb = 0; nb < 4; nb++) {
            bf16x8 bv = *reinterpret_cast<const bf16x8*>(
                Bb + (wc + nb * 16 + ln16) * 32 + qsw * 8);
#pragma unroll
            for (int mb = 0; mb < 4; mb++) {
                if constexpr (QKPATH) acc[mb][nb] = MFMA16(bv, af[mb], acc[mb][nb]);
                else                  acc[mb][nb] = MFMA16(af[mb], bv, acc[mb][nb]);
            }
        }

        __builtin_amdgcn_sched_barrier(0);
        __builtin_amdgcn_s_barrier();          // all waves done reading buf[s%3]
    }

    if constexpr (QKPATH) {
#pragma unroll
        for (int mb = 0; mb < 4; mb++)
#pragma unroll
            for (int nb = 0; nb < 4; nb++) {
                size_t idx = (size_t)(m0 + wr + mb * 16 + ln16) * 2048
                           + (n0 + wc + nb * 16 + quad * 4);
                bf16x4 v;
#pragma unroll
                for (int r = 0; r < 4; r++) v[r] = (bf16)acc[mb][nb][r];
                *reinterpret_cast<bf16x4*>(&qk[idx]) = v;
            }
    } else {
#pragma unroll
        for (int mb = 0; mb < 4; mb++)
#pragma unroll
            for (int nb = 0; nb < 4; nb++) {
                const int e = n0 - 2048 + wc + nb * 16 + ln16;
                size_t idx = (size_t)e * M + (m0 + wr + mb * 16 + quad * 4);
                bf16x4 v;
#pragma unroll
                for (int r = 0; r < 4; r++) v[r] = (bf16)acc[mb][nb][r];
                *reinterpret_cast<bf16x4*>(&vt[idx]) = v;
            }
    }
}

__global__ __launch_bounds__(256)
void gemm_qkv(const bf16* __restrict__ A, const bf16* __restrict__ B,
              bf16* __restrict__ qk, bf16* __restrict__ vt)
{
    __shared__ __align__(16) bf16 As[12288];  // 3 rotating [128][32] buffers
    __shared__ __align__(16) bf16 Bs[12288];
    const int m0 = blockIdx.y * 128, n0 = blockIdx.x * 128;
    if (n0 < 2048) qkv_body<true >(A, B, qk, vt, As, Bs, m0, n0);
    else           qkv_body<false>(A, B, qk, vt, As, Bs, m0, n0);
}

// ---------------------------------------------------------------------------
// Out projection v7 (R4 structure + R10 swizzle, unchanged this round).
__global__ __launch_bounds__(256)
void gemm_out(const bf16* __restrict__ A, const bf16* __restrict__ Bw,
              float* __restrict__ C)
{
    __shared__ __align__(16) bf16 As[24576];  // 3 x [2 k-halves][128][32]
    __shared__ __align__(16) bf16 Bs[12288];  // 3 x [2 k-halves][ 64][32]

    const int t = threadIdx.x;
    const int w = t >> 6, lane = t & 63, quad = lane >> 4, ln16 = lane & 15;

    // bijective XCD swizzle (512 % 8 == 0): XCD c -> m-tiles [4c,4c+4) x n all
    const int bid = blockIdx.x;
    const int xcd = bid & 7, idx = bid >> 3;
    const int m0 = (xcd * 4 + (idx >> 4)) * 128;
    const int n0 = (idx & 15) * 64;

    const int wr = (w >> 1) * 64, wc = (w & 1) * 32;
    const int srow = lane >> 2;
    const int scolsw = (((lane & 3) ^ ((lane >> 3) & 3)) * 8);
    const int qsw = quad ^ ((ln16 >> 1) & 3);

    f32x4 acc[4][2] = {};

    auto stage = [&](int s) {
        const int k0 = s * 64;
        bf16* Ad = As + (s % 3) * 8192;
        bf16* Bd = Bs + (s % 3) * 4096;
#pragma unroll
        for (int p = 0; p < 4; p++) {
            const int i = w * 4 + p;           // 16 ops: h = k-half, o = row grp
            const int h = i >> 3, o = i & 7;
            GLOBAL_LOAD_LDS16(A + (size_t)(m0 + o * 16 + srow) * 1024 + k0 + h * 32 + scolsw,
                              Ad + h * 4096 + o * 512);
        }
#pragma unroll
        for (int p = 0; p < 2; p++) {
            const int i = w * 2 + p;           // 8 ops
            const int h = i >> 2, o = i & 3;
            GLOBAL_LOAD_LDS16(Bw + (size_t)(n0 + o * 16 + srow) * 1024 + k0 + h * 32 + scolsw,
                              Bd + h * 2048 + o * 512);
        }
    };

    stage(0);   // 6 in flight
    stage(1);   // 12 in flight

    for (int s = 0; s < 16; s++) {
        if (s < 14) {
            stage(s + 2);   // 18 in flight; counted wait retires slice s only
            asm volatile("s_waitcnt vmcnt(12)" ::: "memory");
        } else if (s == 14) {
            asm volatile("s_waitcnt vmcnt(6)" ::: "memory");
        } else {
            asm volatile("s_waitcnt vmcnt(0)" ::: "memory");
        }
        __builtin_amdgcn_s_barrier();
        __builtin_amdgcn_sched_barrier(0);

        const bf16* Ab = As + (s % 3) * 8192;
        const bf16* Bb = Bs + (s % 3) * 4096;
#pragma unroll
        for (int kki = 0; kki < 2; kki++) {
            bf16x8 af[4];
#pragma unroll
            for (int mb = 0; mb < 4; mb++)
                af[mb] = *reinterpret_cast<const bf16x8*>(
                    Ab + kki * 4096 + (wr + mb * 16 + ln16) * 32 + qsw * 8);
#pragma unroll
            for (int nb = 0; nb < 2; nb++) {
                bf16x8 bv = *reinterpret_cast<const bf16x8*>(
                    Bb + kki * 2048 + (wc + nb * 16 + ln16) * 32 + qsw * 8);
#pragma unroll
                for (int mb = 0; mb < 4; mb++)
                    acc[mb][nb] = MFMA16(bv, af[mb], acc[mb][nb]);  // swapped
            }
        }

        __builtin_amdgcn_sched_barrier(0);
        __builtin_amdgcn_s_barrier();
    }

    // lane: m = ...+ln16 fixed, n = ...+quad*4 + r -> packed f32x4 stores
#pragma unroll
    for (int mb = 0; mb < 4; mb++)
#pragma unroll
        for (int nb = 0; nb < 2; nb++) {
            size_t idx = (size_t)(m0 + wr + mb * 16 + ln16) * 1024
                       + (n0 + wc + nb * 16 + quad * 4);
            *reinterpret_cast<f32x4*>(&C[idx]) = acc[mb][nb];
        }
}

// ---------------------------------------------------------------------------
// Fused causal flash attention v7 (R11): vones row-sum MFMA replaced by
// per-lane VALU accumulation of the SAME bf16-rounded P values (lane holds
// its q-row's k-slots {nb*16+quad*4+r}; quads partition k) + 2-step
// __shfl_xor(16,32) cross-quad reduce at the end. -2 of 18 MFMAs per kt,
// -4 AGPRs. Numerics: identical addends, different summation order.
__global__ __launch_bounds__(256)
void attn_flash6(const bf16* __restrict__ qk, const bf16* __restrict__ vt,
                 bf16* __restrict__ z)
{
    constexpr int Tn = 2048, Dm = 1024, QLD = 2048, VLD = 4096;
    constexpr int KP = 72;
    __shared__ __align__(16) bf16 Ks[64 * KP];
    __shared__ __align__(16) bf16 VTs[64 * KP];
    __shared__ __align__(16) bf16 Ps[64 * KP];

    const int t = threadIdx.x;
    const int w = t >> 6, lane = t & 63, quad = lane >> 4, ln16 = lane & 15;
    const int q = blockIdx.x >> 5, g = blockIdx.x & 31;
    const int s4 = q >> 3, q0i = q & 7;
    const int j = (s4 == 0) ? q0i : (s4 == 1) ? (15 - q0i)
                : (s4 == 2) ? (16 + q0i) : (31 - q0i);
    const int b = g >> 4, h = g & 15;
    const int q0 = j * 64;

    const bf16* Qb = qk + (size_t)b * Tn * QLD + h * 64;
    const bf16* Kb = Qb + 1024;
    const bf16* Vb = vt + (size_t)(h * 64) * VLD + b * Tn;

    constexpr float C2 = 0.125f * 1.44269504089f;
    bf16x8 qf[2];
#pragma unroll
    for (int kki = 0; kki < 2; kki++) {
        bf16x8 qv = *reinterpret_cast<const bf16x8*>(
            Qb + (size_t)(q0 + w * 16 + ln16) * QLD + kki * 32 + quad * 8);
#pragma unroll
        for (int u = 0; u < 8; u++) qf[kki][u] = (bf16)((float)qv[u] * C2);
    }

    const int sr = t >> 3;
    const int sseg = (t & 7) * 8;

    bf16x8 kreg[2], vreg[2];
#pragma unroll
    for (int p = 0; p < 2; p++) {
        kreg[p] = *reinterpret_cast<const bf16x8*>(Kb + (size_t)(sr + p * 32) * QLD + sseg);
        vreg[p] = *reinterpret_cast<const bf16x8*>(Vb + (size_t)(sr + p * 32) * VLD + sseg);
    }

    f32x4 accO[4] = {};
    float lsum = 0.f;
    const int qloc = w * 16 + ln16;

    for (int kt = 0; kt <= j; kt++) {
        __syncthreads();
#pragma unroll
        for (int p = 0; p < 2; p++) {
            *reinterpret_cast<bf16x8*>(&Ks[(sr + p * 32) * KP + sseg]) = kreg[p];
            *reinterpret_cast<bf16x8*>(&VTs[(sr + p * 32) * KP + sseg]) = vreg[p];
        }
        __syncthreads();

        if (kt < j) {
            const int k1 = (kt + 1) * 64;
#pragma unroll
            for (int p = 0; p < 2; p++) {
                kreg[p] = *reinterpret_cast<const bf16x8*>(
                    Kb + (size_t)(k1 + sr + p * 32) * QLD + sseg);
                vreg[p] = *reinterpret_cast<const bf16x8*>(
                    Vb + (size_t)(sr + p * 32) * VLD + k1 + sseg);
            }
        }

        f32x4 aS[4] = {};
#pragma unroll
        for (int kki = 0; kki < 2; kki++)
#pragma unroll
            for (int nb = 0; nb < 4; nb++) {
                bf16x8 kb = *reinterpret_cast<const bf16x8*>(
                    &Ks[(nb * 16 + ln16) * KP + kki * 32 + quad * 8]);
                aS[nb] = MFMA16(kb, qf[kki], aS[nb]);
            }

        if (kt == j) {
#pragma unroll
            for (int nb = 0; nb < 4; nb++) {
                bf16x4 pv;
#pragma unroll
                for (int r = 0; r < 4; r++) {
                    float p = __builtin_amdgcn_exp2f(aS[nb][r]);
                    if ((nb * 16 + quad * 4 + r) > qloc) p = 0.f;
                    pv[r] = (bf16)p;
                    lsum += (float)pv[r];
                }
                *reinterpret_cast<bf16x4*>(&Ps[qloc * KP + nb * 16 + quad * 4]) = pv;
            }
        } else {
#pragma unroll
            for (int nb = 0; nb < 4; nb++) {
                bf16x4 pv;
#pragma unroll
                for (int r = 0; r < 4; r++) {
                    pv[r] = (bf16)__builtin_amdgcn_exp2f(aS[nb][r]);
                    lsum += (float)pv[r];
                }
                *reinterpret_cast<bf16x4*>(&Ps[qloc * KP + nb * 16 + quad * 4]) = pv;
            }
        }
        asm volatile("s_waitcnt lgkmcnt(0)" ::: "memory");

#pragma unroll
        for (int kki = 0; kki < 2; kki++) {
            bf16x8 pa = *reinterpret_cast<const bf16x8*>(
                &Ps[qloc * KP + kki * 32 + quad * 8]);
#pragma unroll
            for (int nb = 0; nb < 4; nb++) {
                bf16x8 vb = *reinterpret_cast<const bf16x8*>(
                    &VTs[(nb * 16 + ln16) * KP + kki * 32 + quad * 8]);
                accO[nb] = MFMA16(vb, pa, accO[nb]);
            }
        }
    }

    // cross-quad reduce: quads 0-3 (same ln16, same qloc) hold disjoint
    // k-slot partial sums; lanes differ only in bits 4-5.
    lsum += __shfl_xor(lsum, 16, 64);
    lsum += __shfl_xor(lsum, 32, 64);
    const float linv = 1.0f / lsum;

    const size_t zr = ((size_t)b * Tn + q0 + qloc) * Dm + h * 64;
#pragma unroll
    for (int nb = 0; nb < 4; nb++) {
        bf16x4 v;
#pragma unroll
        for (int r = 0; r < 4; r++) v[r] = (bf16)(accO[nb][r] * linv);
        *reinterpret_cast<bf16x4*>(z + zr + nb * 16 + quad * 4) = v;
    }
}

// ---------------------------------------------------------------------------
extern "C" void kernel_launch(void* const* d_in, const int* in_sizes, int n_in,
                              void* d_out, int out_size, void* d_ws, size_t ws_size,
                              hipStream_t stream)
{
    constexpr int B = 2, T = 2048, D = 1024;
    constexpr int M = B * T;  // 4096

    const float* X    = (const float*)d_in[0];
    const float* Wqkv = (const float*)d_in[1];
    const float* Wout = (const float*)d_in[2];
    float* out = (float*)d_out;

    // ws: qk [M][2048] 16 MiB | vt [1024][M] 8 MiB | z [M][1024] 8 MiB
    //   | Woutbf [1024][1024] 2 MiB (own region -- no vt aliasing, so the
    //     Wout conversion can run up front in the fused cvt3)
    bf16* qk  = (bf16*)d_ws;
    bf16* vt  = qk + (size_t)M * 2048;
    bf16* zbf = vt + (size_t)1024 * M;
    bf16* Woutbf = zbf + (size_t)M * 1024;
    // d_out as scratch until gemm_out writes it (Xbf 8 MiB + Wqkvbf 6 MiB <= 16)
    bf16* Xbf    = (bf16*)d_out;
    bf16* Wqkvbf = Xbf + (size_t)M * D;

    dim3 blk(256);
    const int n1 = M * D / 8, n2 = 3 * D * D / 8, n3 = D * D / 8;
    cvt3<<<(n1 + n2 + n3 + 255) / 256, blk, 0, stream>>>(
        X, Wqkv, Wout, Xbf, Woutbf, n1, n1 + n2, n1 + n2 + n3);

    gemm_qkv<<<dim3(24, 32), blk, 0, stream>>>(Xbf, Wqkvbf, qk, vt);

    attn_flash6<<<dim3(1024), blk, 0, stream>>>(qk, vt, zbf);

    gemm_out<<<dim3(512), blk, 0, stream>>>(zbf, Woutbf, out);
}

// Round 13
// 167.439 us; speedup vs baseline: 1.1146x; 1.0442x over previous
//
#include <hip/hip_runtime.h>
#include <hip/hip_bf16.h>

typedef __bf16 bf16;
typedef __bf16 bf16x4 __attribute__((ext_vector_type(4)));
typedef __bf16 bf16x8 __attribute__((ext_vector_type(8)));
typedef float  f32x4 __attribute__((ext_vector_type(4)));

#define MFMA16(a, b, c) __builtin_amdgcn_mfma_f32_16x16x32_bf16((a), (b), (c), 0, 0, 0)

// async 16B/lane global->LDS (m97). LDS dst = uniform base + lane*16.
#define GLOBAL_LOAD_LDS16(gp, lp)                                                     \
    __builtin_amdgcn_global_load_lds(                                                 \
        (const __attribute__((address_space(1))) void*)(gp),                          \
        (__attribute__((address_space(3))) void*)(lp), 16, 0, 0)

// ---------------------------------------------------------------------------
// fp32 -> bf16, three sources in ONE launch (R11, kept: measured gain).
__global__ __launch_bounds__(256)
void cvt3(const float* __restrict__ s1, const float* __restrict__ s2,
          const float* __restrict__ s3, bf16* __restrict__ d12,
          bf16* __restrict__ d3, int n1, int n12, int ntot)
{
    int i = blockIdx.x * 256 + threadIdx.x;
    if (i >= ntot) return;
    const float* s;
    bf16* d;
    if (i < n12) {
        s = (i < n1) ? s1 + (size_t)i * 8 : s2 + (size_t)(i - n1) * 8;
        d = d12 + (size_t)i * 8;
    } else {
        s = s3 + (size_t)(i - n12) * 8;
        d = d3 + (size_t)(i - n12) * 8;
    }
    f32x4 a = *reinterpret_cast<const f32x4*>(s);
    f32x4 b = *reinterpret_cast<const f32x4*>(s + 4);
    bf16x8 r;
#pragma unroll
    for (int u = 0; u < 4; u++) { r[u] = (bf16)a[u]; r[u + 4] = (bf16)b[u]; }
    *reinterpret_cast<bf16x8*>(d) = r;
}

// ---------------------------------------------------------------------------
// QKV projection (R2 T4 pipeline + R10 swizzle, unchanged).
template<bool QKPATH>
__device__ __forceinline__
void qkv_body(const bf16* __restrict__ A, const bf16* __restrict__ B,
              bf16* __restrict__ qk, bf16* __restrict__ vt,
              bf16* As, bf16* Bs, int m0, int n0)
{
    constexpr int M = 4096;
    const int t = threadIdx.x;
    const int w = t >> 6, lane = t & 63, quad = lane >> 4, ln16 = lane & 15;
    const int wr = (w >> 1) * 64, wc = (w & 1) * 64;
    const int srow = lane >> 2;
    const int scolsw = (((lane & 3) ^ ((lane >> 3) & 3)) * 8);
    const int qsw = quad ^ ((ln16 >> 1) & 3);

    f32x4 acc[4][4] = {};

    auto stage = [&](int s) {
        const int kc = s * 32;
        bf16* Ad = As + (s % 3) * 4096;
        bf16* Bd = Bs + (s % 3) * 4096;
#pragma unroll
        for (int p = 0; p < 2; p++) {
            const int o = w * 2 + p;
            GLOBAL_LOAD_LDS16(A + (size_t)(m0 + o * 16 + srow) * 1024 + kc + scolsw,
                              Ad + o * 512);
            GLOBAL_LOAD_LDS16(B + (size_t)(n0 + o * 16 + srow) * 1024 + kc + scolsw,
                              Bd + o * 512);
        }
    };

    stage(0);
    stage(1);

    for (int s = 0; s < 32; s++) {
        if (s < 30) {
            stage(s + 2);
            asm volatile("s_waitcnt vmcnt(8)" ::: "memory");
        } else if (s == 30) {
            asm volatile("s_waitcnt vmcnt(4)" ::: "memory");
        } else {
            asm volatile("s_waitcnt vmcnt(0)" ::: "memory");
        }
        __builtin_amdgcn_s_barrier();
        __builtin_amdgcn_sched_barrier(0);

        const bf16* Ab = As + (s % 3) * 4096;
        const bf16* Bb = Bs + (s % 3) * 4096;
        bf16x8 af[4];
#pragma unroll
        for (int mb = 0; mb < 4; mb++)
            af[mb] = *reinterpret_cast<const bf16x8*>(
                Ab + (wr + mb * 16 + ln16) * 32 + qsw * 8);
#pragma unroll
        for (int nb = 0; nb < 4; nb++) {
            bf16x8 bv = *reinterpret_cast<const bf16x8*>(
                Bb + (wc + nb * 16 + ln16) * 32 + qsw * 8);
#pragma unroll
            for (int mb = 0; mb < 4; mb++) {
                if constexpr (QKPATH) acc[mb][nb] = MFMA16(bv, af[mb], acc[mb][nb]);
                else                  acc[mb][nb] = MFMA16(af[mb], bv, acc[mb][nb]);
            }
        }

        __builtin_amdgcn_sched_barrier(0);
        __builtin_amdgcn_s_barrier();
    }

    if constexpr (QKPATH) {
#pragma unroll
        for (int mb = 0; mb < 4; mb++)
#pragma unroll
            for (int nb = 0; nb < 4; nb++) {
                size_t idx = (size_t)(m0 + wr + mb * 16 + ln16) * 2048
                           + (n0 + wc + nb * 16 + quad * 4);
                bf16x4 v;
#pragma unroll
                for (int r = 0; r < 4; r++) v[r] = (bf16)acc[mb][nb][r];
                *reinterpret_cast<bf16x4*>(&qk[idx]) = v;
            }
    } else {
#pragma unroll
        for (int mb = 0; mb < 4; mb++)
#pragma unroll
            for (int nb = 0; nb < 4; nb++) {
                const int e = n0 - 2048 + wc + nb * 16 + ln16;
                size_t idx = (size_t)e * M + (m0 + wr + mb * 16 + quad * 4);
                bf16x4 v;
#pragma unroll
                for (int r = 0; r < 4; r++) v[r] = (bf16)acc[mb][nb][r];
                *reinterpret_cast<bf16x4*>(&vt[idx]) = v;
            }
    }
}

__global__ __launch_bounds__(256)
void gemm_qkv(const bf16* __restrict__ A, const bf16* __restrict__ B,
              bf16* __restrict__ qk, bf16* __restrict__ vt)
{
    __shared__ __align__(16) bf16 As[12288];  // 3 rotating [128][32] buffers
    __shared__ __align__(16) bf16 Bs[12288];
    const int m0 = blockIdx.y * 128, n0 = blockIdx.x * 128;
    if (n0 < 2048) qkv_body<true >(A, B, qk, vt, As, Bs, m0, n0);
    else           qkv_body<false>(A, B, qk, vt, As, Bs, m0, n0);
}

// ---------------------------------------------------------------------------
// Out projection v7 (R4 structure + R10 swizzle, unchanged).
__global__ __launch_bounds__(256)
void gemm_out(const bf16* __restrict__ A, const bf16* __restrict__ Bw,
              float* __restrict__ C)
{
    __shared__ __align__(16) bf16 As[24576];  // 3 x [2 k-halves][128][32]
    __shared__ __align__(16) bf16 Bs[12288];  // 3 x [2 k-halves][ 64][32]

    const int t = threadIdx.x;
    const int w = t >> 6, lane = t & 63, quad = lane >> 4, ln16 = lane & 15;

    const int bid = blockIdx.x;
    const int xcd = bid & 7, idx = bid >> 3;
    const int m0 = (xcd * 4 + (idx >> 4)) * 128;
    const int n0 = (idx & 15) * 64;

    const int wr = (w >> 1) * 64, wc = (w & 1) * 32;
    const int srow = lane >> 2;
    const int scolsw = (((lane & 3) ^ ((lane >> 3) & 3)) * 8);
    const int qsw = quad ^ ((ln16 >> 1) & 3);

    f32x4 acc[4][2] = {};

    auto stage = [&](int s) {
        const int k0 = s * 64;
        bf16* Ad = As + (s % 3) * 8192;
        bf16* Bd = Bs + (s % 3) * 4096;
#pragma unroll
        for (int p = 0; p < 4; p++) {
            const int i = w * 4 + p;
            const int h = i >> 3, o = i & 7;
            GLOBAL_LOAD_LDS16(A + (size_t)(m0 + o * 16 + srow) * 1024 + k0 + h * 32 + scolsw,
                              Ad + h * 4096 + o * 512);
        }
#pragma unroll
        for (int p = 0; p < 2; p++) {
            const int i = w * 2 + p;
            const int h = i >> 2, o = i & 3;
            GLOBAL_LOAD_LDS16(Bw + (size_t)(n0 + o * 16 + srow) * 1024 + k0 + h * 32 + scolsw,
                              Bd + h * 2048 + o * 512);
        }
    };

    stage(0);
    stage(1);

    for (int s = 0; s < 16; s++) {
        if (s < 14) {
            stage(s + 2);
            asm volatile("s_waitcnt vmcnt(12)" ::: "memory");
        } else if (s == 14) {
            asm volatile("s_waitcnt vmcnt(6)" ::: "memory");
        } else {
            asm volatile("s_waitcnt vmcnt(0)" ::: "memory");
        }
        __builtin_amdgcn_s_barrier();
        __builtin_amdgcn_sched_barrier(0);

        const bf16* Ab = As + (s % 3) * 8192;
        const bf16* Bb = Bs + (s % 3) * 4096;
#pragma unroll
        for (int kki = 0; kki < 2; kki++) {
            bf16x8 af[4];
#pragma unroll
            for (int mb = 0; mb < 4; mb++)
                af[mb] = *reinterpret_cast<const bf16x8*>(
                    Ab + kki * 4096 + (wr + mb * 16 + ln16) * 32 + qsw * 8);
#pragma unroll
            for (int nb = 0; nb < 2; nb++) {
                bf16x8 bv = *reinterpret_cast<const bf16x8*>(
                    Bb + kki * 2048 + (wc + nb * 16 + ln16) * 32 + qsw * 8);
#pragma unroll
                for (int mb = 0; mb < 4; mb++)
                    acc[mb][nb] = MFMA16(bv, af[mb], acc[mb][nb]);  // swapped
            }
        }

        __builtin_amdgcn_sched_barrier(0);
        __builtin_amdgcn_s_barrier();
    }

#pragma unroll
    for (int mb = 0; mb < 4; mb++)
#pragma unroll
        for (int nb = 0; nb < 2; nb++) {
            size_t idx = (size_t)(m0 + wr + mb * 16 + ln16) * 1024
                       + (n0 + wc + nb * 16 + quad * 4);
            *reinterpret_cast<f32x4*>(&C[idx]) = acc[mb][nb];
        }
}

// ---------------------------------------------------------------------------
// Fused causal flash attention v8 (R12):
//  * lsum VALU row-sum REVERTED to vones MFMA (R11 measured regression:
//    matrix pipe was idle, VALU was the busy pipe).
//  * K/V double-buffered in LDS -> ONE __syncthreads per kt (was two):
//    write buf[kt&1] -> sync -> prefetch kt+1 (overlaps compute) -> QK/PV.
//    Hazard: between barriers only {compute(kt-1) on buf[(kt-1)&1],
//    write(kt) on buf[kt&1]} coexist -- disjoint. Ps rows are wave-private
//    (row = w*16+ln16), so wave-local lgkmcnt(0) suffices (as before).
//  * Stride-64 rows + 16B-slot XOR swizzle (elem ^= (row&7)<<3) replace the
//    KP=72 pad; legal since staging is register ds_write (not gload_lds).
//    LDS = 2x8K(K) + 2x8K(V) + 4K(P) elems = 40960 B = exactly 4 blocks/CU.
__global__ __launch_bounds__(256)
void attn_flash8(const bf16* __restrict__ qk, const bf16* __restrict__ vt,
                 bf16* __restrict__ z)
{
    constexpr int Tn = 2048, Dm = 1024, QLD = 2048, VLD = 4096;
    __shared__ __align__(16) bf16 Ks[8192];   // 2 x [64][64], swizzled
    __shared__ __align__(16) bf16 VTs[8192];  // 2 x [64][64], swizzled
    __shared__ __align__(16) bf16 Ps[4096];   // [64][64], wave-private rows

    const int t = threadIdx.x;
    const int w = t >> 6, lane = t & 63, quad = lane >> 4, ln16 = lane & 15;
    const int q = blockIdx.x >> 5, g = blockIdx.x & 31;
    const int s4 = q >> 3, q0i = q & 7;
    const int j = (s4 == 0) ? q0i : (s4 == 1) ? (15 - q0i)
                : (s4 == 2) ? (16 + q0i) : (31 - q0i);
    const int b = g >> 4, h = g & 15;
    const int q0 = j * 64;

    const bf16* Qb = qk + (size_t)b * Tn * QLD + h * 64;
    const bf16* Kb = Qb + 1024;
    const bf16* Vb = vt + (size_t)(h * 64) * VLD + b * Tn;

    constexpr float C2 = 0.125f * 1.44269504089f;
    bf16x8 qf[2];
#pragma unroll
    for (int kki = 0; kki < 2; kki++) {
        bf16x8 qv = *reinterpret_cast<const bf16x8*>(
            Qb + (size_t)(q0 + w * 16 + ln16) * QLD + kki * 32 + quad * 8);
#pragma unroll
        for (int u = 0; u < 8; u++) qf[kki][u] = (bf16)((float)qv[u] * C2);
    }

    bf16x8 vones;
#pragma unroll
    for (int u = 0; u < 8; u++) vones[u] = (bf16)1.0f;

    const int sr = t >> 3;            // staging row 0..31 (+p*32)
    const int sseg = (t & 7) * 8;     // staging col (elems)
    const int rsw = (ln16 & 7) << 3;  // read-side swizzle (row&7 == ln16&7)

    bf16x8 kreg[2], vreg[2];
#pragma unroll
    for (int p = 0; p < 2; p++) {
        kreg[p] = *reinterpret_cast<const bf16x8*>(Kb + (size_t)(sr + p * 32) * QLD + sseg);
        vreg[p] = *reinterpret_cast<const bf16x8*>(Vb + (size_t)(sr + p * 32) * VLD + sseg);
    }

    f32x4 accO[5] = {};
    const int qloc = w * 16 + ln16;

    for (int kt = 0; kt <= j; kt++) {
        const int cur = (kt & 1) * 4096;
        // write K/V tile kt into ping-pong buffer (register ds_write, swizzled)
#pragma unroll
        for (int p = 0; p < 2; p++) {
            const int r = sr + p * 32;
            const int co = sseg ^ ((r & 7) << 3);
            *reinterpret_cast<bf16x8*>(&Ks[cur + r * 64 + co]) = kreg[p];
            *reinterpret_cast<bf16x8*>(&VTs[cur + r * 64 + co]) = vreg[p];
        }
        __syncthreads();   // single barrier per kt

        if (kt < j) {      // global prefetch kt+1, hides under QK/PV below
            const int k1 = (kt + 1) * 64;
#pragma unroll
            for (int p = 0; p < 2; p++) {
                kreg[p] = *reinterpret_cast<const bf16x8*>(
                    Kb + (size_t)(k1 + sr + p * 32) * QLD + sseg);
                vreg[p] = *reinterpret_cast<const bf16x8*>(
                    Vb + (size_t)(sr + p * 32) * VLD + k1 + sseg);
            }
        }

        f32x4 aS[4] = {};
#pragma unroll
        for (int kki = 0; kki < 2; kki++)
#pragma unroll
            for (int nb = 0; nb < 4; nb++) {
                bf16x8 kb = *reinterpret_cast<const bf16x8*>(
                    &Ks[cur + (nb * 16 + ln16) * 64 + ((kki * 32 + quad * 8) ^ rsw)]);
                aS[nb] = MFMA16(kb, qf[kki], aS[nb]);
            }

        if (kt == j) {
#pragma unroll
            for (int nb = 0; nb < 4; nb++) {
                bf16x4 pv;
#pragma unroll
                for (int r = 0; r < 4; r++) {
                    float p = __builtin_amdgcn_exp2f(aS[nb][r]);
                    if ((nb * 16 + quad * 4 + r) > qloc) p = 0.f;
                    pv[r] = (bf16)p;
                }
                *reinterpret_cast<bf16x4*>(
                    &Ps[qloc * 64 + ((nb * 16 + quad * 4) ^ rsw)]) = pv;
            }
        } else {
#pragma unroll
            for (int nb = 0; nb < 4; nb++) {
                bf16x4 pv;
#pragma unroll
                for (int r = 0; r < 4; r++)
                    pv[r] = (bf16)__builtin_amdgcn_exp2f(aS[nb][r]);
                *reinterpret_cast<bf16x4*>(
                    &Ps[qloc * 64 + ((nb * 16 + quad * 4) ^ rsw)]) = pv;
            }
        }
        asm volatile("s_waitcnt lgkmcnt(0)" ::: "memory");

#pragma unroll
        for (int kki = 0; kki < 2; kki++) {
            bf16x8 pa = *reinterpret_cast<const bf16x8*>(
                &Ps[qloc * 64 + ((kki * 32 + quad * 8) ^ rsw)]);
#pragma unroll
            for (int nb = 0; nb < 4; nb++) {
                bf16x8 vb = *reinterpret_cast<const bf16x8*>(
                    &VTs[cur + (nb * 16 + ln16) * 64 + ((kki * 32 + quad * 8) ^ rsw)]);
                accO[nb] = MFMA16(vb, pa, accO[nb]);
            }
            accO[4] = MFMA16(vones, pa, accO[4]);
        }
    }

    const float linv = 1.0f / accO[4][0];
    const size_t zr = ((size_t)b * Tn + q0 + qloc) * Dm + h * 64;
#pragma unroll
    for (int nb = 0; nb < 4; nb++) {
        bf16x4 v;
#pragma unroll
        for (int r = 0; r < 4; r++) v[r] = (bf16)(accO[nb][r] * linv);
        *reinterpret_cast<bf16x4*>(z + zr + nb * 16 + quad * 4) = v;
    }
}

// ---------------------------------------------------------------------------
extern "C" void kernel_launch(void* const* d_in, const int* in_sizes, int n_in,
                              void* d_out, int out_size, void* d_ws, size_t ws_size,
                              hipStream_t stream)
{
    constexpr int B = 2, T = 2048, D = 1024;
    constexpr int M = B * T;  // 4096

    const float* X    = (const float*)d_in[0];
    const float* Wqkv = (const float*)d_in[1];
    const float* Wout = (const float*)d_in[2];
    float* out = (float*)d_out;

    // ws: qk [M][2048] 16 MiB | vt [1024][M] 8 MiB | z [M][1024] 8 MiB
    //   | Woutbf [1024][1024] 2 MiB
    bf16* qk  = (bf16*)d_ws;
    bf16* vt  = qk + (size_t)M * 2048;
    bf16* zbf = vt + (size_t)1024 * M;
    bf16* Woutbf = zbf + (size_t)M * 1024;
    // d_out as scratch until gemm_out writes it (Xbf 8 MiB + Wqkvbf 6 MiB <= 16)
    bf16* Xbf    = (bf16*)d_out;
    bf16* Wqkvbf = Xbf + (size_t)M * D;

    dim3 blk(256);
    const int n1 = M * D / 8, n2 = 3 * D * D / 8, n3 = D * D / 8;
    cvt3<<<(n1 + n2 + n3 + 255) / 256, blk, 0, stream>>>(
        X, Wqkv, Wout, Xbf, Woutbf, n1, n1 + n2, n1 + n2 + n3);

    gemm_qkv<<<dim3(24, 32), blk, 0, stream>>>(Xbf, Wqkvbf, qk, vt);

    attn_flash8<<<dim3(1024), blk, 0, stream>>>(qk, vt, zbf);

    gemm_out<<<dim3(512), blk, 0, stream>>>(zbf, Woutbf, out);
}

// Round 16
// 164.185 us; speedup vs baseline: 1.1366x; 1.0198x over previous
//
#include <hip/hip_runtime.h>
#include <hip/hip_bf16.h>

typedef __bf16 bf16;
typedef __bf16 bf16x4 __attribute__((ext_vector_type(4)));
typedef __bf16 bf16x8 __attribute__((ext_vector_type(8)));
typedef float  f32x4 __attribute__((ext_vector_type(4)));

#define MFMA16(a, b, c) __builtin_amdgcn_mfma_f32_16x16x32_bf16((a), (b), (c), 0, 0, 0)

// async 16B/lane global->LDS (m97). LDS dst = uniform base + lane*16.
#define GLOBAL_LOAD_LDS16(gp, lp)                                                     \
    __builtin_amdgcn_global_load_lds(                                                 \
        (const __attribute__((address_space(1))) void*)(gp),                          \
        (__attribute__((address_space(3))) void*)(lp), 16, 0, 0)

// ---------------------------------------------------------------------------
// fp32 -> bf16, three sources in ONE launch (R11, kept: measured gain).
__global__ __launch_bounds__(256)
void cvt3(const float* __restrict__ s1, const float* __restrict__ s2,
          const float* __restrict__ s3, bf16* __restrict__ d12,
          bf16* __restrict__ d3, int n1, int n12, int ntot)
{
    int i = blockIdx.x * 256 + threadIdx.x;
    if (i >= ntot) return;
    const float* s;
    bf16* d;
    if (i < n12) {
        s = (i < n1) ? s1 + (size_t)i * 8 : s2 + (size_t)(i - n1) * 8;
        d = d12 + (size_t)i * 8;
    } else {
        s = s3 + (size_t)(i - n12) * 8;
        d = d3 + (size_t)(i - n12) * 8;
    }
    f32x4 a = *reinterpret_cast<const f32x4*>(s);
    f32x4 b = *reinterpret_cast<const f32x4*>(s + 4);
    bf16x8 r;
#pragma unroll
    for (int u = 0; u < 4; u++) { r[u] = (bf16)a[u]; r[u + 4] = (bf16)b[u]; }
    *reinterpret_cast<bf16x8*>(d) = r;
}

// ---------------------------------------------------------------------------
// QKV projection (R2 T4 pipeline + R10 swizzle, unchanged; R13 counters:
// bank-conflicts 0, MfmaUtil 24%).
template<bool QKPATH>
__device__ __forceinline__
void qkv_body(const bf16* __restrict__ A, const bf16* __restrict__ B,
              bf16* __restrict__ qk, bf16* __restrict__ vt,
              bf16* As, bf16* Bs, int m0, int n0)
{
    constexpr int M = 4096;
    const int t = threadIdx.x;
    const int w = t >> 6, lane = t & 63, quad = lane >> 4, ln16 = lane & 15;
    const int wr = (w >> 1) * 64, wc = (w & 1) * 64;
    const int srow = lane >> 2;
    const int scolsw = (((lane & 3) ^ ((lane >> 3) & 3)) * 8);
    const int qsw = quad ^ ((ln16 >> 1) & 3);

    f32x4 acc[4][4] = {};

    auto stage = [&](int s) {
        const int kc = s * 32;
        bf16* Ad = As + (s % 3) * 4096;
        bf16* Bd = Bs + (s % 3) * 4096;
#pragma unroll
        for (int p = 0; p < 2; p++) {
            const int o = w * 2 + p;
            GLOBAL_LOAD_LDS16(A + (size_t)(m0 + o * 16 + srow) * 1024 + kc + scolsw,
                              Ad + o * 512);
            GLOBAL_LOAD_LDS16(B + (size_t)(n0 + o * 16 + srow) * 1024 + kc + scolsw,
                              Bd + o * 512);
        }
    };

    stage(0);
    stage(1);

    for (int s = 0; s < 32; s++) {
        if (s < 30) {
            stage(s + 2);
            asm volatile("s_waitcnt vmcnt(8)" ::: "memory");
        } else if (s == 30) {
            asm volatile("s_waitcnt vmcnt(4)" ::: "memory");
        } else {
            asm volatile("s_waitcnt vmcnt(0)" ::: "memory");
        }
        __builtin_amdgcn_s_barrier();
        __builtin_amdgcn_sched_barrier(0);

        const bf16* Ab = As + (s % 3) * 4096;
        const bf16* Bb = Bs + (s % 3) * 4096;
        bf16x8 af[4];
#pragma unroll
        for (int mb = 0; mb < 4; mb++)
            af[mb] = *reinterpret_cast<const bf16x8*>(
                Ab + (wr + mb * 16 + ln16) * 32 + qsw * 8);
#pragma unroll
        for (int nb = 0; nb < 4; nb++) {
            bf16x8 bv = *reinterpret_cast<const bf16x8*>(
                Bb + (wc + nb * 16 + ln16) * 32 + qsw * 8);
#pragma unroll
            for (int mb = 0; mb < 4; mb++) {
                if constexpr (QKPATH) acc[mb][nb] = MFMA16(bv, af[mb], acc[mb][nb]);
                else                  acc[mb][nb] = MFMA16(af[mb], bv, acc[mb][nb]);
            }
        }

        __builtin_amdgcn_sched_barrier(0);
        __builtin_amdgcn_s_barrier();
    }

    if constexpr (QKPATH) {
#pragma unroll
        for (int mb = 0; mb < 4; mb++)
#pragma unroll
            for (int nb = 0; nb < 4; nb++) {
                size_t idx = (size_t)(m0 + wr + mb * 16 + ln16) * 2048
                           + (n0 + wc + nb * 16 + quad * 4);
                bf16x4 v;
#pragma unroll
                for (int r = 0; r < 4; r++) v[r] = (bf16)acc[mb][nb][r];
                *reinterpret_cast<bf16x4*>(&qk[idx]) = v;
            }
    } else {
#pragma unroll
        for (int mb = 0; mb < 4; mb++)
#pragma unroll
            for (int nb = 0; nb < 4; nb++) {
                const int e = n0 - 2048 + wc + nb * 16 + ln16;
                size_t idx = (size_t)e * M + (m0 + wr + mb * 16 + quad * 4);
                bf16x4 v;
#pragma unroll
                for (int r = 0; r < 4; r++) v[r] = (bf16)acc[mb][nb][r];
                *reinterpret_cast<bf16x4*>(&vt[idx]) = v;
            }
    }
}

__global__ __launch_bounds__(256)
void gemm_qkv(const bf16* __restrict__ A, const bf16* __restrict__ B,
              bf16* __restrict__ qk, bf16* __restrict__ vt)
{
    __shared__ __align__(16) bf16 As[12288];  // 3 rotating [128][32] buffers
    __shared__ __align__(16) bf16 Bs[12288];
    const int m0 = blockIdx.y * 128, n0 = blockIdx.x * 128;
    if (n0 < 2048) qkv_body<true >(A, B, qk, vt, As, Bs, m0, n0);
    else           qkv_body<false>(A, B, qk, vt, As, Bs, m0, n0);
}

// ---------------------------------------------------------------------------
// Out projection v7 (R4 structure + R10 swizzle, unchanged).
__global__ __launch_bounds__(256)
void gemm_out(const bf16* __restrict__ A, const bf16* __restrict__ Bw,
              float* __restrict__ C)
{
    __shared__ __align__(16) bf16 As[24576];  // 3 x [2 k-halves][128][32]
    __shared__ __align__(16) bf16 Bs[12288];  // 3 x [2 k-halves][ 64][32]

    const int t = threadIdx.x;
    const int w = t >> 6, lane = t & 63, quad = lane >> 4, ln16 = lane & 15;

    const int bid = blockIdx.x;
    const int xcd = bid & 7, idx = bid >> 3;
    const int m0 = (xcd * 4 + (idx >> 4)) * 128;
    const int n0 = (idx & 15) * 64;

    const int wr = (w >> 1) * 64, wc = (w & 1) * 32;
    const int srow = lane >> 2;
    const int scolsw = (((lane & 3) ^ ((lane >> 3) & 3)) * 8);
    const int qsw = quad ^ ((ln16 >> 1) & 3);

    f32x4 acc[4][2] = {};

    auto stage = [&](int s) {
        const int k0 = s * 64;
        bf16* Ad = As + (s % 3) * 8192;
        bf16* Bd = Bs + (s % 3) * 4096;
#pragma unroll
        for (int p = 0; p < 4; p++) {
            const int i = w * 4 + p;
            const int h = i >> 3, o = i & 7;
            GLOBAL_LOAD_LDS16(A + (size_t)(m0 + o * 16 + srow) * 1024 + k0 + h * 32 + scolsw,
                              Ad + h * 4096 + o * 512);
        }
#pragma unroll
        for (int p = 0; p < 2; p++) {
            const int i = w * 2 + p;
            const int h = i >> 2, o = i & 3;
            GLOBAL_LOAD_LDS16(Bw + (size_t)(n0 + o * 16 + srow) * 1024 + k0 + h * 32 + scolsw,
                              Bd + h * 2048 + o * 512);
        }
    };

    stage(0);
    stage(1);

    for (int s = 0; s < 16; s++) {
        if (s < 14) {
            stage(s + 2);
            asm volatile("s_waitcnt vmcnt(12)" ::: "memory");
        } else if (s == 14) {
            asm volatile("s_waitcnt vmcnt(6)" ::: "memory");
        } else {
            asm volatile("s_waitcnt vmcnt(0)" ::: "memory");
        }
        __builtin_amdgcn_s_barrier();
        __builtin_amdgcn_sched_barrier(0);

        const bf16* Ab = As + (s % 3) * 8192;
        const bf16* Bb = Bs + (s % 3) * 4096;
#pragma unroll
        for (int kki = 0; kki < 2; kki++) {
            bf16x8 af[4];
#pragma unroll
            for (int mb = 0; mb < 4; mb++)
                af[mb] = *reinterpret_cast<const bf16x8*>(
                    Ab + kki * 4096 + (wr + mb * 16 + ln16) * 32 + qsw * 8);
#pragma unroll
            for (int nb = 0; nb < 2; nb++) {
                bf16x8 bv = *reinterpret_cast<const bf16x8*>(
                    Bb + kki * 2048 + (wc + nb * 16 + ln16) * 32 + qsw * 8);
#pragma unroll
                for (int mb = 0; mb < 4; mb++)
                    acc[mb][nb] = MFMA16(bv, af[mb], acc[mb][nb]);  // swapped
            }
        }

        __builtin_amdgcn_sched_barrier(0);
        __builtin_amdgcn_s_barrier();
    }

#pragma unroll
    for (int mb = 0; mb < 4; mb++)
#pragma unroll
        for (int nb = 0; nb < 2; nb++) {
            size_t idx = (size_t)(m0 + wr + mb * 16 + ln16) * 1024
                       + (n0 + wc + nb * 16 + quad * 4);
            *reinterpret_cast<f32x4*>(&C[idx]) = acc[mb][nb];
        }
}

// ---------------------------------------------------------------------------
// Fused causal flash attention v9 (R14): TWO q-tiles per block, paired
// (j1 = qp, j2 = 31-qp) -> uniform 33 tiles of MFMA work per block; each
// staged K/V tile + barrier feeds 2x the MFMA (36 vs 18/wave); K/V global
// traffic halves. Sync structure is v8's proven single-barrier dbuf,
// UNCHANGED. The kt<=j1 gate is block-uniform. Grid 512 (2/CU), LDS 48KB,
// Ps per tile (wave-private rows, wave-local lgkmcnt as before).
__global__ __launch_bounds__(256)
void attn_flash9(const bf16* __restrict__ qk, const bf16* __restrict__ vt,
                 bf16* __restrict__ z)
{
    constexpr int Tn = 2048, Dm = 1024, QLD = 2048, VLD = 4096;
    __shared__ __align__(16) bf16 Ks[8192];   // 2 x [64][64], swizzled
    __shared__ __align__(16) bf16 VTs[8192];  // 2 x [64][64], swizzled
    __shared__ __align__(16) bf16 Ps1[4096];  // [64][64], tile-1 P
    __shared__ __align__(16) bf16 Ps2[4096];  // [64][64], tile-2 P

    const int t = threadIdx.x;
    const int w = t >> 6, lane = t & 63, quad = lane >> 4, ln16 = lane & 15;
    const int qp = blockIdx.x >> 5, g = blockIdx.x & 31;
    const int j1 = qp, j2 = 31 - qp;          // j1 <= 15 < j2
    const int b = g >> 4, h = g & 15;
    const int q01 = j1 * 64, q02 = j2 * 64;

    const bf16* Qb = qk + (size_t)b * Tn * QLD + h * 64;
    const bf16* Kb = Qb + 1024;
    const bf16* Vb = vt + (size_t)(h * 64) * VLD + b * Tn;

    constexpr float C2 = 0.125f * 1.44269504089f;
    bf16x8 qf1[2], qf2[2];
#pragma unroll
    for (int kki = 0; kki < 2; kki++) {
        bf16x8 qv1 = *reinterpret_cast<const bf16x8*>(
            Qb + (size_t)(q01 + w * 16 + ln16) * QLD + kki * 32 + quad * 8);
        bf16x8 qv2 = *reinterpret_cast<const bf16x8*>(
            Qb + (size_t)(q02 + w * 16 + ln16) * QLD + kki * 32 + quad * 8);
#pragma unroll
        for (int u = 0; u < 8; u++) {
            qf1[kki][u] = (bf16)((float)qv1[u] * C2);
            qf2[kki][u] = (bf16)((float)qv2[u] * C2);
        }
    }

    bf16x8 vones;
#pragma unroll
    for (int u = 0; u < 8; u++) vones[u] = (bf16)1.0f;

    const int sr = t >> 3;            // staging row 0..31 (+p*32)
    const int sseg = (t & 7) * 8;     // staging col (elems)
    const int rsw = (ln16 & 7) << 3;  // read-side swizzle (row&7 == ln16&7)

    bf16x8 kreg[2], vreg[2];
#pragma unroll
    for (int p = 0; p < 2; p++) {
        kreg[p] = *reinterpret_cast<const bf16x8*>(Kb + (size_t)(sr + p * 32) * QLD + sseg);
        vreg[p] = *reinterpret_cast<const bf16x8*>(Vb + (size_t)(sr + p * 32) * VLD + sseg);
    }

    f32x4 accO1[5] = {}, accO2[5] = {};
    const int qloc = w * 16 + ln16;

    for (int kt = 0; kt <= j2; kt++) {
        const int cur = (kt & 1) * 4096;
#pragma unroll
        for (int p = 0; p < 2; p++) {
            const int r = sr + p * 32;
            const int co = sseg ^ ((r & 7) << 3);
            *reinterpret_cast<bf16x8*>(&Ks[cur + r * 64 + co]) = kreg[p];
            *reinterpret_cast<bf16x8*>(&VTs[cur + r * 64 + co]) = vreg[p];
        }
        __syncthreads();   // single barrier per kt (v8 structure)

        if (kt < j2) {     // global prefetch kt+1, hides under QK/PV below
            const int k1 = (kt + 1) * 64;
#pragma unroll
            for (int p = 0; p < 2; p++) {
                kreg[p] = *reinterpret_cast<const bf16x8*>(
                    Kb + (size_t)(k1 + sr + p * 32) * QLD + sseg);
                vreg[p] = *reinterpret_cast<const bf16x8*>(
                    Vb + (size_t)(sr + p * 32) * VLD + k1 + sseg);
            }
        }
        const bool t1 = (kt <= j1);   // block-uniform

        // ---- QK^T tile 2 (always) ----
        f32x4 aS2[4] = {};
#pragma unroll
        for (int kki = 0; kki < 2; kki++)
#pragma unroll
            for (int nb = 0; nb < 4; nb++) {
                bf16x8 kb = *reinterpret_cast<const bf16x8*>(
                    &Ks[cur + (nb * 16 + ln16) * 64 + ((kki * 32 + quad * 8) ^ rsw)]);
                aS2[nb] = MFMA16(kb, qf2[kki], aS2[nb]);
            }
        if (kt == j2) {
#pragma unroll
            for (int nb = 0; nb < 4; nb++) {
                bf16x4 pv;
#pragma unroll
                for (int r = 0; r < 4; r++) {
                    float p = __builtin_amdgcn_exp2f(aS2[nb][r]);
                    if ((nb * 16 + quad * 4 + r) > qloc) p = 0.f;
                    pv[r] = (bf16)p;
                }
                *reinterpret_cast<bf16x4*>(
                    &Ps2[qloc * 64 + ((nb * 16 + quad * 4) ^ rsw)]) = pv;
            }
        } else {
#pragma unroll
            for (int nb = 0; nb < 4; nb++) {
                bf16x4 pv;
#pragma unroll
                for (int r = 0; r < 4; r++)
                    pv[r] = (bf16)__builtin_amdgcn_exp2f(aS2[nb][r]);
                *reinterpret_cast<bf16x4*>(
                    &Ps2[qloc * 64 + ((nb * 16 + quad * 4) ^ rsw)]) = pv;
            }
        }

        // ---- QK^T tile 1 (while active) ----
        if (t1) {
            f32x4 aS1[4] = {};
#pragma unroll
            for (int kki = 0; kki < 2; kki++)
#pragma unroll
                for (int nb = 0; nb < 4; nb++) {
                    bf16x8 kb = *reinterpret_cast<const bf16x8*>(
                        &Ks[cur + (nb * 16 + ln16) * 64 + ((kki * 32 + quad * 8) ^ rsw)]);
                    aS1[nb] = MFMA16(kb, qf1[kki], aS1[nb]);
                }
            if (kt == j1) {
#pragma unroll
                for (int nb = 0; nb < 4; nb++) {
                    bf16x4 pv;
#pragma unroll
                    for (int r = 0; r < 4; r++) {
                        float p = __builtin_amdgcn_exp2f(aS1[nb][r]);
                        if ((nb * 16 + quad * 4 + r) > qloc) p = 0.f;
                        pv[r] = (bf16)p;
                    }
                    *reinterpret_cast<bf16x4*>(
                        &Ps1[qloc * 64 + ((nb * 16 + quad * 4) ^ rsw)]) = pv;
                }
            } else {
#pragma unroll
                for (int nb = 0; nb < 4; nb++) {
                    bf16x4 pv;
#pragma unroll
                    for (int r = 0; r < 4; r++)
                        pv[r] = (bf16)__builtin_amdgcn_exp2f(aS1[nb][r]);
                    *reinterpret_cast<bf16x4*>(
                        &Ps1[qloc * 64 + ((nb * 16 + quad * 4) ^ rsw)]) = pv;
                }
            }
        }
        asm volatile("s_waitcnt lgkmcnt(0)" ::: "memory");

        // ---- PV (tile 2 always, tile 1 while active) ----
#pragma unroll
        for (int kki = 0; kki < 2; kki++) {
            bf16x8 pa2 = *reinterpret_cast<const bf16x8*>(
                &Ps2[qloc * 64 + ((kki * 32 + quad * 8) ^ rsw)]);
#pragma unroll
            for (int nb = 0; nb < 4; nb++) {
                bf16x8 vb = *reinterpret_cast<const bf16x8*>(
                    &VTs[cur + (nb * 16 + ln16) * 64 + ((kki * 32 + quad * 8) ^ rsw)]);
                accO2[nb] = MFMA16(vb, pa2, accO2[nb]);
            }
            accO2[4] = MFMA16(vones, pa2, accO2[4]);
        }
        if (t1) {
#pragma unroll
            for (int kki = 0; kki < 2; kki++) {
                bf16x8 pa1 = *reinterpret_cast<const bf16x8*>(
                    &Ps1[qloc * 64 + ((kki * 32 + quad * 8) ^ rsw)]);
#pragma unroll
                for (int nb = 0; nb < 4; nb++) {
                    bf16x8 vb = *reinterpret_cast<const bf16x8*>(
                        &VTs[cur + (nb * 16 + ln16) * 64 + ((kki * 32 + quad * 8) ^ rsw)]);
                    accO1[nb] = MFMA16(vb, pa1, accO1[nb]);
                }
                accO1[4] = MFMA16(vones, pa1, accO1[4]);
            }
        }
    }

    const float linv1 = 1.0f / accO1[4][0];
    const float linv2 = 1.0f / accO2[4][0];
    const size_t zr1 = ((size_t)b * Tn + q01 + qloc) * Dm + h * 64;
    const size_t zr2 = ((size_t)b * Tn + q02 + qloc) * Dm + h * 64;
#pragma unroll
    for (int nb = 0; nb < 4; nb++) {
        bf16x4 v1, v2;
#pragma unroll
        for (int r = 0; r < 4; r++) {
            v1[r] = (bf16)(accO1[nb][r] * linv1);
            v2[r] = (bf16)(accO2[nb][r] * linv2);
        }
        *reinterpret_cast<bf16x4*>(z + zr1 + nb * 16 + quad * 4) = v1;
        *reinterpret_cast<bf16x4*>(z + zr2 + nb * 16 + quad * 4) = v2;
    }
}

// ---------------------------------------------------------------------------
extern "C" void kernel_launch(void* const* d_in, const int* in_sizes, int n_in,
                              void* d_out, int out_size, void* d_ws, size_t ws_size,
                              hipStream_t stream)
{
    constexpr int B = 2, T = 2048, D = 1024;
    constexpr int M = B * T;  // 4096

    const float* X    = (const float*)d_in[0];
    const float* Wqkv = (const float*)d_in[1];
    const float* Wout = (const float*)d_in[2];
    float* out = (float*)d_out;

    // ws: qk [M][2048] 16 MiB | vt [1024][M] 8 MiB | z [M][1024] 8 MiB
    //   | Woutbf [1024][1024] 2 MiB
    bf16* qk  = (bf16*)d_ws;
    bf16* vt  = qk + (size_t)M * 2048;
    bf16* zbf = vt + (size_t)1024 * M;
    bf16* Woutbf = zbf + (size_t)M * 1024;
    // d_out as scratch until gemm_out writes it (Xbf 8 MiB + Wqkvbf 6 MiB <= 16)
    bf16* Xbf    = (bf16*)d_out;
    bf16* Wqkvbf = Xbf + (size_t)M * D;

    dim3 blk(256);
    const int n1 = M * D / 8, n2 = 3 * D * D / 8, n3 = D * D / 8;
    cvt3<<<(n1 + n2 + n3 + 255) / 256, blk, 0, stream>>>(
        X, Wqkv, Wout, Xbf, Woutbf, n1, n1 + n2, n1 + n2 + n3);

    gemm_qkv<<<dim3(24, 32), blk, 0, stream>>>(Xbf, Wqkvbf, qk, vt);

    attn_flash9<<<dim3(512), blk, 0, stream>>>(qk, vt, zbf);

    gemm_out<<<dim3(512), blk, 0, stream>>>(zbf, Woutbf, out);
}